// Round 1
// baseline (295.802 us; speedup 1.0000x reference)
//
#include <hip/hip_runtime.h>
#include <hip/hip_cooperative_groups.h>
#include <hip/hip_bf16.h>
#include <math.h>

namespace cg = cooperative_groups;

// Problem constants: H=8, d_model=256, N=128, d_k=32, B=32, rows=4096

typedef short short8 __attribute__((ext_vector_type(8)));
typedef float f32x4 __attribute__((ext_vector_type(4)));

union V8 { uint4 u; short8 s; };

__device__ __forceinline__ float gelu_f(float x) {
    float inner = 0.7978845608028654f * (x + 0.044715f * x * x * x);
    return 0.5f * x * (1.0f + tanhf(inner));
}
__device__ __forceinline__ void split_bf16(float x, ushort& h, ushort& l) {
    __hip_bfloat16 bh = __float2bfloat16(x);          // RN
    float hf = __bfloat162float(bh);
    __hip_bfloat16 bl = __float2bfloat16(x - hf);
    h = __builtin_bit_cast(ushort, bh);
    l = __builtin_bit_cast(ushort, bl);
}
__device__ __forceinline__ ushort bf16bits(float x) {
    return __builtin_bit_cast(ushort, __float2bfloat16(x));
}
__device__ __forceinline__ float bits_to_f(ushort v) {
    return __builtin_bit_cast(float, ((uint)v) << 16);
}
__device__ __forceinline__ short8 lds_frag(const ushort* p) {
    V8 v; v.u = *(const uint4*)p; return v.s;
}

// Frag layout for all prepped weights: elem (k,n) of mat m lives at
//   m*65536 + ((tg*8+ks)*64 + lane)*8 + j
// with tg=n>>4, lr=n&15, ks=k>>5, quad=(k>>3)&3, j=k&7, lane=quad*16+lr.
// Mats: 0=mlp_w1 1=mlp_w2 2=wq 3=wk 4=wv 5=out_w 6=fc_out_w[0:256] 7=[256:512]

// ---------------------------------------------------------------------------
// Single cooperative kernel, 256 blocks x 512 thr, 5 phases via grid.sync():
//  P0 wprep (128 blocks, 1 job each)
//  P1 featproj (128 half-jobs on blocks 0..127) + fused3 (all 256 blocks)
//  P2 conn (256 tiles)
//  P3 attn (512 jobs, 2 per block in thread halves) -> bf16 hi/lo out
//  P4 out-proj GEMM (LDS-free, fragments straight from global)
// ---------------------------------------------------------------------------
__global__ __launch_bounds__(512) void k_mega(
    const float* __restrict__ X, const float* __restrict__ gumbel_u,
    const float* __restrict__ memory_w, const float* __restrict__ fc_out_w,
    const float* __restrict__ fc_out_b, const float* __restrict__ fc_cat_w,
    const float* __restrict__ fc_cat_b,
    const float* __restrict__ wq, const float* __restrict__ Bq,
    const float* __restrict__ wk, const float* __restrict__ Bk,
    const float* __restrict__ wv, const float* __restrict__ Bv,
    const float* __restrict__ out_w, const float* __restrict__ out_b,
    const float* __restrict__ mlp_w1, const float* __restrict__ b1,
    const float* __restrict__ mlp_w2, const float* __restrict__ b2,
    float* __restrict__ A, float* __restrict__ Bm,
    ushort* __restrict__ maskb,
    ushort* __restrict__ Qn, ushort* __restrict__ Kn, ushort* __restrict__ Vt,
    ushort* __restrict__ aoHi, ushort* __restrict__ aoLo,
    ushort* __restrict__ wf_hi, ushort* __restrict__ wf_lo,
    float* __restrict__ out) {
    cg::grid_group grid = cg::this_grid();
    __shared__ __align__(16) union {
        struct { float xs[32 * 132]; } w;                             // 16.9 KB
        struct { ushort aHi[16 * 264], aLo[16 * 264],
                        bHi[16 * 264], bLo[16 * 264]; } g;            // 33.8 KB
        struct { float sA[16 * 260], sB[32 * 260]; } c;               // 49.9 KB
        struct { ushort ps[2][64 * 136]; } a;                         // 34.8 KB
    } sm;
    int bx = blockIdx.x, t = threadIdx.x;
    int lane = t & 63, w = t >> 6, lr = lane & 15, quad = lane >> 4;

    // ================= P0: weight prep (blocks 0..127) =================
    if (bx < 128) {
        int m = bx >> 4, ks = (bx >> 1) & 7, nh = bx & 1;
        const float* W = m == 0 ? mlp_w1 : m == 1 ? mlp_w2 : m == 2 ? wq :
                         m == 3 ? wk : m == 4 ? wv : m == 5 ? out_w :
                         m == 6 ? fc_out_w : fc_out_w + 65536;
        ushort* Hm = wf_hi + m * 65536;
        ushort* Lm = wf_lo + m * 65536;
        float* xs = sm.w.xs;
        #pragma unroll
        for (int p = 0; p < 2; ++p) {
            int idx = p * 512 + t;
            int row = idx >> 5, c4 = (idx & 31) * 4;
            *(float4*)(xs + row * 132 + c4) =
                *(const float4*)(W + (ks * 32 + row) * 256 + nh * 128 + c4);
        }
        __syncthreads();
        int tg = nh * 8 + w;
        int nl = w * 16 + lr;
        ushort hb[8], lb[8];
        #pragma unroll
        for (int j = 0; j < 8; ++j)
            split_bf16(xs[(quad * 8 + j) * 132 + nl], hb[j], lb[j]);
        uint4 ph = { (uint)hb[0] | ((uint)hb[1] << 16), (uint)hb[2] | ((uint)hb[3] << 16),
                     (uint)hb[4] | ((uint)hb[5] << 16), (uint)hb[6] | ((uint)hb[7] << 16) };
        uint4 pl = { (uint)lb[0] | ((uint)lb[1] << 16), (uint)lb[2] | ((uint)lb[3] << 16),
                     (uint)lb[4] | ((uint)lb[5] << 16), (uint)lb[6] | ((uint)lb[7] << 16) };
        int idx = ((tg * 8 + ks) * 64 + lane) * 8;
        *(uint4*)(Hm + idx) = ph;
        *(uint4*)(Lm + idx) = pl;
    }
    grid.sync();

    // ================= P1a: featproj (blocks 0..127, half-job) =========
    if (bx < 128) {
        int rt = bx >> 1, half = bx & 1;
        #pragma unroll
        for (int ii = 0; ii < 2; ++ii) {
            int f4 = ii * 512 + t;
            int rr = f4 >> 6, c = (f4 & 63) * 4;
            int r = rt * 16 + rr;
            int hh = r >> 7, n = r & 127;
            float4 xv = *(const float4*)(memory_w + n * 2048 + hh * 256 + c);
            ushort h4[4], l4[4];
            split_bf16(xv.x, h4[0], l4[0]); split_bf16(xv.y, h4[1], l4[1]);
            split_bf16(xv.z, h4[2], l4[2]); split_bf16(xv.w, h4[3], l4[3]);
            uint2 ph = { (uint)h4[0] | ((uint)h4[1] << 16), (uint)h4[2] | ((uint)h4[3] << 16) };
            uint2 pl = { (uint)l4[0] | ((uint)l4[1] << 16), (uint)l4[2] | ((uint)l4[3] << 16) };
            *(uint2*)(sm.g.aHi + rr * 264 + c) = ph;
            *(uint2*)(sm.g.aLo + rr * 264 + c) = pl;
        }
        __syncthreads();
        int msel = w & 1, wp = w >> 1;
        const uint4* H4 = (const uint4*)(wf_hi + (6 + msel) * 65536);
        const uint4* L4 = (const uint4*)(wf_lo + (6 + msel) * 65536);
        const ushort* ah = sm.g.aHi + lr * 264 + quad * 8;
        const ushort* al = sm.g.aLo + lr * 264 + quad * 8;
        float* O = msel ? Bm : A;
        #pragma unroll
        for (int i2 = 0; i2 < 2; ++i2) {
            int tg = half * 8 + wp * 2 + i2;
            f32x4 acc = {};
            #pragma unroll
            for (int ks = 0; ks < 8; ++ks) {
                short8 a_h = lds_frag(ah + ks * 32);
                short8 a_l = lds_frag(al + ks * 32);
                int off = (tg * 8 + ks) * 64 + lane;
                V8 bh, bl; bh.u = H4[off]; bl.u = L4[off];
                acc = __builtin_amdgcn_mfma_f32_16x16x32_bf16(a_h, bh.s, acc, 0, 0, 0);
                acc = __builtin_amdgcn_mfma_f32_16x16x32_bf16(a_l, bh.s, acc, 0, 0, 0);
                acc = __builtin_amdgcn_mfma_f32_16x16x32_bf16(a_h, bl.s, acc, 0, 0, 0);
            }
            int n0 = tg * 16 + lr;
            #pragma unroll
            for (int r = 0; r < 4; ++r)
                O[(rt * 16 + quad * 4 + r) * 256 + n0] = acc[r];
        }
        __syncthreads();   // all waves done reading LDS before fused3 restages
    }

    // ================= P1b: fused3 (all 256 blocks) ====================
    {
        int r0 = bx * 16;
        #pragma unroll
        for (int ii = 0; ii < 2; ++ii) {
            int f4 = ii * 512 + t;
            int row = f4 >> 6, c = (f4 & 63) * 4;
            float4 xv = *(const float4*)(X + (r0 + row) * 256 + c);
            ushort h4[4], l4[4];
            split_bf16(xv.x, h4[0], l4[0]); split_bf16(xv.y, h4[1], l4[1]);
            split_bf16(xv.z, h4[2], l4[2]); split_bf16(xv.w, h4[3], l4[3]);
            uint2 ph = { (uint)h4[0] | ((uint)h4[1] << 16), (uint)h4[2] | ((uint)h4[3] << 16) };
            uint2 pl = { (uint)l4[0] | ((uint)l4[1] << 16), (uint)l4[2] | ((uint)l4[3] << 16) };
            *(uint2*)(sm.g.aHi + row * 264 + c) = ph;
            *(uint2*)(sm.g.aLo + row * 264 + c) = pl;
        }
        __syncthreads();
        int aoff = lr * 264 + quad * 8;
        // stage 1: mlp1 + gelu
        {
            const uint4* H4 = (const uint4*)(wf_hi + 0 * 65536);
            const uint4* L4 = (const uint4*)(wf_lo + 0 * 65536);
            f32x4 acc[2] = {};
            #pragma unroll
            for (int ks = 0; ks < 8; ++ks) {
                short8 a_h = lds_frag(sm.g.aHi + aoff + ks * 32);
                short8 a_l = lds_frag(sm.g.aLo + aoff + ks * 32);
                #pragma unroll
                for (int ti = 0; ti < 2; ++ti) {
                    int off = ((w * 2 + ti) * 8 + ks) * 64 + lane;
                    V8 bh, bl; bh.u = H4[off]; bl.u = L4[off];
                    acc[ti] = __builtin_amdgcn_mfma_f32_16x16x32_bf16(a_h, bh.s, acc[ti], 0, 0, 0);
                    acc[ti] = __builtin_amdgcn_mfma_f32_16x16x32_bf16(a_l, bh.s, acc[ti], 0, 0, 0);
                    acc[ti] = __builtin_amdgcn_mfma_f32_16x16x32_bf16(a_h, bl.s, acc[ti], 0, 0, 0);
                }
            }
            #pragma unroll
            for (int ti = 0; ti < 2; ++ti) {
                int n0 = (w * 2 + ti) * 16 + lr;
                float bb = b1[n0];
                #pragma unroll
                for (int r = 0; r < 4; ++r) {
                    float o = gelu_f(acc[ti][r] + bb);
                    ushort hh, ll; split_bf16(o, hh, ll);
                    int ad = (quad * 4 + r) * 264 + n0;
                    sm.g.bHi[ad] = hh; sm.g.bLo[ad] = ll;
                }
            }
        }
        __syncthreads();
        // stage 2: mlp2
        {
            const uint4* H4 = (const uint4*)(wf_hi + 1 * 65536);
            const uint4* L4 = (const uint4*)(wf_lo + 1 * 65536);
            f32x4 acc[2] = {};
            #pragma unroll
            for (int ks = 0; ks < 8; ++ks) {
                short8 a_h = lds_frag(sm.g.bHi + aoff + ks * 32);
                short8 a_l = lds_frag(sm.g.bLo + aoff + ks * 32);
                #pragma unroll
                for (int ti = 0; ti < 2; ++ti) {
                    int off = ((w * 2 + ti) * 8 + ks) * 64 + lane;
                    V8 bh, bl; bh.u = H4[off]; bl.u = L4[off];
                    acc[ti] = __builtin_amdgcn_mfma_f32_16x16x32_bf16(a_h, bh.s, acc[ti], 0, 0, 0);
                    acc[ti] = __builtin_amdgcn_mfma_f32_16x16x32_bf16(a_l, bh.s, acc[ti], 0, 0, 0);
                    acc[ti] = __builtin_amdgcn_mfma_f32_16x16x32_bf16(a_h, bl.s, acc[ti], 0, 0, 0);
                }
            }
            __syncthreads();
            #pragma unroll
            for (int ti = 0; ti < 2; ++ti) {
                int n0 = (w * 2 + ti) * 16 + lr;
                float bb = b2[n0];
                #pragma unroll
                for (int r = 0; r < 4; ++r) {
                    float o = acc[ti][r] + bb;
                    ushort hh, ll; split_bf16(o, hh, ll);
                    int ad = (quad * 4 + r) * 264 + n0;
                    sm.g.aHi[ad] = hh; sm.g.aLo[ad] = ll;
                }
            }
        }
        __syncthreads();
        // stage 3: qkv -> bf16 global, per-head layouts (V pre-transposed)
        {
            const uint4* Hq = (const uint4*)(wf_hi + 2 * 65536);
            const uint4* Lq = (const uint4*)(wf_lo + 2 * 65536);
            const uint4* Hk = (const uint4*)(wf_hi + 3 * 65536);
            const uint4* Lk = (const uint4*)(wf_lo + 3 * 65536);
            const uint4* Hv = (const uint4*)(wf_hi + 4 * 65536);
            const uint4* Lv = (const uint4*)(wf_lo + 4 * 65536);
            f32x4 aq[2] = {}, ak[2] = {}, av[2] = {};
            #pragma unroll 2
            for (int ks = 0; ks < 8; ++ks) {
                short8 a_h = lds_frag(sm.g.aHi + aoff + ks * 32);
                short8 a_l = lds_frag(sm.g.aLo + aoff + ks * 32);
                #pragma unroll
                for (int ti = 0; ti < 2; ++ti) {
                    int off = ((w * 2 + ti) * 8 + ks) * 64 + lane;
                    V8 qh, ql, kh, kl, vh, vl;
                    qh.u = Hq[off]; ql.u = Lq[off];
                    kh.u = Hk[off]; kl.u = Lk[off];
                    vh.u = Hv[off]; vl.u = Lv[off];
                    aq[ti] = __builtin_amdgcn_mfma_f32_16x16x32_bf16(a_h, qh.s, aq[ti], 0, 0, 0);
                    aq[ti] = __builtin_amdgcn_mfma_f32_16x16x32_bf16(a_l, qh.s, aq[ti], 0, 0, 0);
                    aq[ti] = __builtin_amdgcn_mfma_f32_16x16x32_bf16(a_h, ql.s, aq[ti], 0, 0, 0);
                    ak[ti] = __builtin_amdgcn_mfma_f32_16x16x32_bf16(a_h, kh.s, ak[ti], 0, 0, 0);
                    ak[ti] = __builtin_amdgcn_mfma_f32_16x16x32_bf16(a_l, kh.s, ak[ti], 0, 0, 0);
                    ak[ti] = __builtin_amdgcn_mfma_f32_16x16x32_bf16(a_h, kl.s, ak[ti], 0, 0, 0);
                    av[ti] = __builtin_amdgcn_mfma_f32_16x16x32_bf16(a_h, vh.s, av[ti], 0, 0, 0);
                    av[ti] = __builtin_amdgcn_mfma_f32_16x16x32_bf16(a_l, vh.s, av[ti], 0, 0, 0);
                    av[ti] = __builtin_amdgcn_mfma_f32_16x16x32_bf16(a_h, vl.s, av[ti], 0, 0, 0);
                }
            }
            #pragma unroll
            for (int ti = 0; ti < 2; ++ti) {
                int n0 = (w * 2 + ti) * 16 + lr;
                int hh = n0 >> 5, dk = n0 & 31;
                float vbq = Bq[n0], vbk = Bk[n0], vbv = Bv[n0];
                #pragma unroll
                for (int r = 0; r < 4; ++r) {
                    int row = r0 + quad * 4 + r;
                    int bb = row >> 7, n = row & 127;
                    int bh_ = bb * 8 + hh;
                    Qn[(bh_ * 128 + n) * 32 + dk] = bf16bits(aq[ti][r] + vbq);
                    Kn[(bh_ * 128 + n) * 32 + dk] = bf16bits(ak[ti][r] + vbk);
                    Vt[(bh_ * 32 + dk) * 128 + n] = bf16bits(av[ti][r] + vbv);
                }
            }
        }
    }
    grid.sync();

    // ================= P2: conn (256 tiles) ============================
    {
        int h = bx >> 5;
        int rem = bx & 31;
        int it = rem >> 3, jt = rem & 7;
        int i0 = it * 32, j0 = jt * 16;
        int jl = t & 15, il = t >> 4;
        #pragma unroll
        for (int p = 0; p < 6; ++p) {
            int id2 = p * 512 + t;
            if (id2 < 1024) {
                int rr = id2 >> 6, c = (id2 & 63) * 4;
                *(float4*)(sm.c.sA + rr * 260 + c) =
                    *(const float4*)(A + (h * 128 + j0 + rr) * 256 + c);
            } else {
                int id3 = id2 - 1024;
                int rr = id3 >> 6, c = (id3 & 63) * 4;
                float4 bvv = *(const float4*)(Bm + (h * 128 + i0 + rr) * 256 + c);
                float4 fb = *(const float4*)(fc_out_b + c);
                bvv.x += fb.x; bvv.y += fb.y; bvv.z += fb.z; bvv.w += fb.w;
                *(float4*)(sm.c.sB + rr * 260 + c) = bvv;
            }
        }
        __syncthreads();
        const float* Ar = sm.c.sA + jl * 260;
        const float* Br = sm.c.sB + il * 260;
        float l0 = fc_cat_b[0], l1 = fc_cat_b[1];
        #pragma unroll 4
        for (int d4 = 0; d4 < 64; ++d4) {
            int d = d4 * 4;
            float4 avv = *(const float4*)(Ar + d);
            float4 bvv = *(const float4*)(Br + d);
            float4 cwA = *(const float4*)(fc_cat_w + d * 2);
            float4 cwB = *(const float4*)(fc_cat_w + d * 2 + 4);
            float h0 = fmaxf(avv.x + bvv.x, 0.f);
            float h1 = fmaxf(avv.y + bvv.y, 0.f);
            float h2 = fmaxf(avv.z + bvv.z, 0.f);
            float h3 = fmaxf(avv.w + bvv.w, 0.f);
            l0 += h0 * cwA.x + h1 * cwA.z + h2 * cwB.x + h3 * cwB.z;
            l1 += h0 * cwA.y + h1 * cwA.w + h2 * cwB.y + h3 * cwB.w;
        }
        int i = i0 + il, j = j0 + jl;
        float2 uu = *(const float2*)(gumbel_u + ((h * 128 + i) * 128 + j) * 2);
        float g0 = -logf(-logf(uu.x + 1e-10f) + 1e-10f);
        float g1 = -logf(-logf(uu.y + 1e-10f) + 1e-10f);
        bool on = (l1 + g1) > (l0 + g0);
        maskb[(h * 128 + i) * 128 + j] = bf16bits(on ? 0.f : -1e9f);
    }
    grid.sync();

    // ================= P3: attention (2 jobs/block) ====================
    {
        int jh = t >> 8;                     // 0/1: independent 256-thr jobs
        int job = bx * 2 + jh;               // 0..511
        int b = job >> 4, h = (job >> 1) & 7, rh = job & 1;
        int w4 = w & 3;
        int rt = rh * 4 + w4;
        int bh_ = b * 8 + h;
        ushort* ps = sm.a.ps[jh];
        V8 af;
        af.u = *(const uint4*)(Qn + (bh_ * 128 + rt * 16 + lr) * 32 + quad * 8);
        f32x4 s[8];
        #pragma unroll
        for (int ct = 0; ct < 8; ++ct) {
            V8 bf_;
            bf_.u = *(const uint4*)(Kn + (bh_ * 128 + ct * 16 + lr) * 32 + quad * 8);
            f32x4 z = {0.f, 0.f, 0.f, 0.f};
            s[ct] = __builtin_amdgcn_mfma_f32_16x16x32_bf16(af.s, bf_.s, z, 0, 0, 0);
        }
        const float scale = 0.17677669529663687f;  // 32^-0.5
        const ushort* mrow = maskb + h * 16384;
        #pragma unroll
        for (int r = 0; r < 4; ++r) {
            int lrow = w4 * 16 + quad * 4 + r;
            int grow = rt * 16 + quad * 4 + r;
            float sv[8];
            float mx = -3.0e38f;
            #pragma unroll
            for (int ct = 0; ct < 8; ++ct) {
                float bias = bits_to_f(mrow[grow * 128 + ct * 16 + lr]);
                sv[ct] = s[ct][r] * scale + bias;
                mx = fmaxf(mx, sv[ct]);
            }
            mx = fmaxf(mx, __shfl_xor(mx, 1));
            mx = fmaxf(mx, __shfl_xor(mx, 2));
            mx = fmaxf(mx, __shfl_xor(mx, 4));
            mx = fmaxf(mx, __shfl_xor(mx, 8));
            float sum = 0.f;
            #pragma unroll
            for (int ct = 0; ct < 8; ++ct) {
                sv[ct] = __expf(sv[ct] - mx);
                sum += sv[ct];
            }
            sum += __shfl_xor(sum, 1);
            sum += __shfl_xor(sum, 2);
            sum += __shfl_xor(sum, 4);
            sum += __shfl_xor(sum, 8);
            float iv = 1.f / sum;
            #pragma unroll
            for (int ct = 0; ct < 8; ++ct)
                ps[lrow * 136 + ct * 16 + lr] = bf16bits(sv[ct] * iv);
        }
        f32x4 o0 = {}, o1 = {};
        #pragma unroll
        for (int kk = 0; kk < 4; ++kk) {
            short8 pa = lds_frag(ps + (w4 * 16 + lr) * 136 + kk * 32 + quad * 8);
            V8 v0, v1;
            v0.u = *(const uint4*)(Vt + (bh_ * 32 + lr) * 128 + kk * 32 + quad * 8);
            v1.u = *(const uint4*)(Vt + (bh_ * 32 + 16 + lr) * 128 + kk * 32 + quad * 8);
            o0 = __builtin_amdgcn_mfma_f32_16x16x32_bf16(pa, v0.s, o0, 0, 0, 0);
            o1 = __builtin_amdgcn_mfma_f32_16x16x32_bf16(pa, v1.s, o1, 0, 0, 0);
        }
        #pragma unroll
        for (int r = 0; r < 4; ++r) {
            int grow = rt * 16 + quad * 4 + r;
            int base = (b * 128 + grow) * 256 + h * 32;
            ushort hh, ll;
            split_bf16(o0[r], hh, ll);
            aoHi[base + lr] = hh; aoLo[base + lr] = ll;
            split_bf16(o1[r], hh, ll);
            aoHi[base + 16 + lr] = hh; aoLo[base + 16 + lr] = ll;
        }
    }
    grid.sync();

    // ================= P4: out-proj GEMM (LDS-free) ====================
    {
        int r0 = bx * 16;
        const uint4* H4 = (const uint4*)(wf_hi + 5 * 65536);
        const uint4* L4 = (const uint4*)(wf_lo + 5 * 65536);
        f32x4 acc[2] = {};
        #pragma unroll
        for (int ks = 0; ks < 8; ++ks) {
            V8 ahv, alv;
            ahv.u = *(const uint4*)(aoHi + (r0 + lr) * 256 + ks * 32 + quad * 8);
            alv.u = *(const uint4*)(aoLo + (r0 + lr) * 256 + ks * 32 + quad * 8);
            #pragma unroll
            for (int ti = 0; ti < 2; ++ti) {
                int off = ((w * 2 + ti) * 8 + ks) * 64 + lane;
                V8 bh, bl; bh.u = H4[off]; bl.u = L4[off];
                acc[ti] = __builtin_amdgcn_mfma_f32_16x16x32_bf16(ahv.s, bh.s, acc[ti], 0, 0, 0);
                acc[ti] = __builtin_amdgcn_mfma_f32_16x16x32_bf16(alv.s, bh.s, acc[ti], 0, 0, 0);
                acc[ti] = __builtin_amdgcn_mfma_f32_16x16x32_bf16(ahv.s, bl.s, acc[ti], 0, 0, 0);
            }
        }
        #pragma unroll
        for (int ti = 0; ti < 2; ++ti) {
            int n0 = (w * 2 + ti) * 16 + lr;
            float bs = out_b[n0];
            #pragma unroll
            for (int r = 0; r < 4; ++r)
                out[(r0 + quad * 4 + r) * 256 + n0] = acc[ti][r] + bs;
        }
    }
}

// ---------------------------------------------------------------------------
extern "C" void kernel_launch(void* const* d_in, const int* in_sizes, int n_in,
                              void* d_out, int out_size, void* d_ws, size_t ws_size,
                              hipStream_t stream) {
    const float* x        = (const float*)d_in[0];
    const float* gumbel_u = (const float*)d_in[1];
    const float* memory_w = (const float*)d_in[2];
    const float* fc_out_w = (const float*)d_in[3];
    const float* fc_out_b = (const float*)d_in[4];
    const float* fc_cat_w = (const float*)d_in[5];
    const float* fc_cat_b = (const float*)d_in[6];
    const float* wq       = (const float*)d_in[7];
    const float* bq       = (const float*)d_in[8];
    const float* wk       = (const float*)d_in[9];
    const float* bk       = (const float*)d_in[10];
    const float* wv_      = (const float*)d_in[11];
    const float* bv_      = (const float*)d_in[12];
    const float* out_w    = (const float*)d_in[13];
    const float* out_b    = (const float*)d_in[14];
    const float* mlp_w1   = (const float*)d_in[15];
    const float* mlp_b1   = (const float*)d_in[16];
    const float* mlp_w2   = (const float*)d_in[17];
    const float* mlp_b2   = (const float*)d_in[18];

    // Workspace (float offsets).
    float* ws     = (float*)d_ws;
    float* A      = ws;                        //        0 .. 262144
    float* Bm     = ws + 262144;               //   262144 .. 524288
    ushort* mask  = (ushort*)(ws + 524288);    //   524288 .. 557056 (65536 u16)
    ushort* qn    = (ushort*)(ws + 589824);    //   589824 .. 1114112
    ushort* kn    = (ushort*)(ws + 1114112);   //  1114112 .. 1638400
    ushort* vt    = (ushort*)(ws + 1638400);   //  1638400 .. 2162688
    ushort* aoHi  = (ushort*)(ws + 2162688);   //  2162688 .. 2686976
    ushort* aoLo  = (ushort*)(ws + 2686976);   //  2686976 .. 3211264
    ushort* wf_hi = (ushort*)(ws + 3211264);   //  3211264 .. 3473408
    ushort* wf_lo = wf_hi + 8 * 65536;         //  3473408 .. 3735552
    float* out    = (float*)d_out;

    void* args[] = {
        (void*)&x, (void*)&gumbel_u, (void*)&memory_w, (void*)&fc_out_w,
        (void*)&fc_out_b, (void*)&fc_cat_w, (void*)&fc_cat_b,
        (void*)&wq, (void*)&bq, (void*)&wk, (void*)&bk,
        (void*)&wv_, (void*)&bv_, (void*)&out_w, (void*)&out_b,
        (void*)&mlp_w1, (void*)&mlp_b1, (void*)&mlp_w2, (void*)&mlp_b2,
        (void*)&A, (void*)&Bm, (void*)&mask, (void*)&qn, (void*)&kn, (void*)&vt,
        (void*)&aoHi, (void*)&aoLo, (void*)&wf_hi, (void*)&wf_lo, (void*)&out };
    hipLaunchCooperativeKernel((const void*)k_mega, dim3(256), dim3(512),
                               args, 0, stream);
}

// Round 3
// 154.901 us; speedup vs baseline: 1.9096x; 1.9096x over previous
//
#include <hip/hip_runtime.h>
#include <hip/hip_bf16.h>
#include <math.h>

// Problem constants: H=8, d_model=256, N=128, d_k=32, B=32, rows=4096

typedef short short8 __attribute__((ext_vector_type(8)));
typedef float f32x4 __attribute__((ext_vector_type(4)));

union V8 { uint4 u; short8 s; };

__device__ __forceinline__ float gelu_f(float x) {
    float inner = 0.7978845608028654f * (x + 0.044715f * x * x * x);
    return 0.5f * x * (1.0f + tanhf(inner));
}
__device__ __forceinline__ void split_bf16(float x, ushort& h, ushort& l) {
    __hip_bfloat16 bh = __float2bfloat16(x);          // RN
    float hf = __bfloat162float(bh);
    __hip_bfloat16 bl = __float2bfloat16(x - hf);
    h = __builtin_bit_cast(ushort, bh);
    l = __builtin_bit_cast(ushort, bl);
}
__device__ __forceinline__ ushort bf16bits(float x) {
    return __builtin_bit_cast(ushort, __float2bfloat16(x));
}
__device__ __forceinline__ float bits_to_f(ushort v) {
    return __builtin_bit_cast(float, ((uint)v) << 16);
}
__device__ __forceinline__ short8 lds_frag(const ushort* p) {
    V8 v; v.u = *(const uint4*)p; return v.s;
}

// Frag layout for all prepped weights: elem (k,n) of mat m lives at
//   m*65536 + ((tg*8+ks)*64 + lane)*8 + j
// with tg=n>>4, lr=n&15, ks=k>>5, quad=(k>>3)&3, j=k&7, lane=quad*16+lr.
// Mats: 0=mlp_w1 1=mlp_w2 2=wq 3=wk 4=wv 5=out_w 6=fc_out_w[0:256] 7=[256:512]

// ---------------------------------------------------------------------------
// Dispatch 1: wprep. 128 blocks x 512 thr, one (m,ks,nh) job per block.
// MUST be its own dispatch: later kernels read its output.
// ---------------------------------------------------------------------------
__global__ __launch_bounds__(512) void k_wprep(
    const float* __restrict__ mlp_w1, const float* __restrict__ mlp_w2,
    const float* __restrict__ wq, const float* __restrict__ wk,
    const float* __restrict__ wv, const float* __restrict__ out_w,
    const float* __restrict__ fc_out_w,
    ushort* __restrict__ hi, ushort* __restrict__ lo) {
    __shared__ __align__(16) float xs[32 * 132];
    int bx = blockIdx.x, t = threadIdx.x;
    int m = bx >> 4, ks = (bx >> 1) & 7, nh = bx & 1;
    const float* W = m == 0 ? mlp_w1 : m == 1 ? mlp_w2 : m == 2 ? wq :
                     m == 3 ? wk : m == 4 ? wv : m == 5 ? out_w :
                     m == 6 ? fc_out_w : fc_out_w + 65536;
    ushort* Hm = hi + m * 65536;
    ushort* Lm = lo + m * 65536;
    #pragma unroll
    for (int p = 0; p < 2; ++p) {
        int idx = p * 512 + t;
        int row = idx >> 5, c4 = (idx & 31) * 4;
        *(float4*)(xs + row * 132 + c4) =
            *(const float4*)(W + (ks * 32 + row) * 256 + nh * 128 + c4);
    }
    __syncthreads();
    int lane = t & 63, w = t >> 6, lr = lane & 15, quad = lane >> 4;
    int tg = nh * 8 + w;
    int nl = w * 16 + lr;
    ushort hb[8], lb[8];
    #pragma unroll
    for (int j = 0; j < 8; ++j)
        split_bf16(xs[(quad * 8 + j) * 132 + nl], hb[j], lb[j]);
    uint4 ph = { (uint)hb[0] | ((uint)hb[1] << 16), (uint)hb[2] | ((uint)hb[3] << 16),
                 (uint)hb[4] | ((uint)hb[5] << 16), (uint)hb[6] | ((uint)hb[7] << 16) };
    uint4 pl = { (uint)lb[0] | ((uint)lb[1] << 16), (uint)lb[2] | ((uint)lb[3] << 16),
                 (uint)lb[4] | ((uint)lb[5] << 16), (uint)lb[6] | ((uint)lb[7] << 16) };
    int idx = ((tg * 8 + ks) * 64 + lane) * 8;
    *(uint4*)(Hm + idx) = ph;
    *(uint4*)(Lm + idx) = pl;
}

// ---------------------------------------------------------------------------
// Dispatch 2: featproj (quarter-job per block, balanced) + fused3
// (mlp1->mlp2->qkv, per-head bf16 layouts, V pre-transposed).
// 256 blocks x 512 thr.
// ---------------------------------------------------------------------------
__global__ __launch_bounds__(512) void k_p2(
    const float* __restrict__ memory_w, const float* __restrict__ X,
    const ushort* __restrict__ Whi, const ushort* __restrict__ Wlo,
    const float* __restrict__ b1, const float* __restrict__ b2,
    const float* __restrict__ Bq, const float* __restrict__ Bk,
    const float* __restrict__ Bv,
    float* __restrict__ A, float* __restrict__ Bm,
    ushort* __restrict__ Qn, ushort* __restrict__ Kn, ushort* __restrict__ Vt) {
    __shared__ __align__(16) struct {
        ushort aHi[16 * 264], aLo[16 * 264];
        ushort bHi[16 * 264], bLo[16 * 264];
    } sm;                                                 // 33.8 KB
    int bx = blockIdx.x, t = threadIdx.x;
    int lane = t & 63, w = t >> 6, lr = lane & 15, quad = lane >> 4;

    // ---- featproj quarter-job: rt = bx>>2, tasks (bx&3)*8 + w ----
    {
        int rt = bx >> 2;
        #pragma unroll
        for (int ii = 0; ii < 2; ++ii) {
            int f4 = ii * 512 + t;
            int rr = f4 >> 6, c = (f4 & 63) * 4;
            int r = rt * 16 + rr;
            int hh = r >> 7, n = r & 127;
            float4 xv = *(const float4*)(memory_w + n * 2048 + hh * 256 + c);
            ushort h4[4], l4[4];
            split_bf16(xv.x, h4[0], l4[0]); split_bf16(xv.y, h4[1], l4[1]);
            split_bf16(xv.z, h4[2], l4[2]); split_bf16(xv.w, h4[3], l4[3]);
            uint2 ph = { (uint)h4[0] | ((uint)h4[1] << 16), (uint)h4[2] | ((uint)h4[3] << 16) };
            uint2 pl = { (uint)l4[0] | ((uint)l4[1] << 16), (uint)l4[2] | ((uint)l4[3] << 16) };
            *(uint2*)(sm.aHi + rr * 264 + c) = ph;
            *(uint2*)(sm.aLo + rr * 264 + c) = pl;
        }
        __syncthreads();
        int task = (bx & 3) * 8 + w;          // 0..31
        int msel = task >> 4, tg = task & 15;
        const uint4* H4 = (const uint4*)(Whi + (6 + msel) * 65536);
        const uint4* L4 = (const uint4*)(Wlo + (6 + msel) * 65536);
        const ushort* ah = sm.aHi + lr * 264 + quad * 8;
        const ushort* al = sm.aLo + lr * 264 + quad * 8;
        float* O = msel ? Bm : A;
        f32x4 acc = {};
        #pragma unroll
        for (int ks = 0; ks < 8; ++ks) {
            short8 a_h = lds_frag(ah + ks * 32);
            short8 a_l = lds_frag(al + ks * 32);
            int off = (tg * 8 + ks) * 64 + lane;
            V8 bh, bl; bh.u = H4[off]; bl.u = L4[off];
            acc = __builtin_amdgcn_mfma_f32_16x16x32_bf16(a_h, bh.s, acc, 0, 0, 0);
            acc = __builtin_amdgcn_mfma_f32_16x16x32_bf16(a_l, bh.s, acc, 0, 0, 0);
            acc = __builtin_amdgcn_mfma_f32_16x16x32_bf16(a_h, bl.s, acc, 0, 0, 0);
        }
        int n0 = tg * 16 + lr;
        #pragma unroll
        for (int r = 0; r < 4; ++r)
            O[(rt * 16 + quad * 4 + r) * 256 + n0] = acc[r];
        __syncthreads();   // LDS reuse barrier before fused3 restages
    }

    // ---- fused3 ----
    int r0 = bx * 16;
    #pragma unroll
    for (int ii = 0; ii < 2; ++ii) {
        int f4 = ii * 512 + t;
        int row = f4 >> 6, c = (f4 & 63) * 4;
        float4 xv = *(const float4*)(X + (r0 + row) * 256 + c);
        ushort h4[4], l4[4];
        split_bf16(xv.x, h4[0], l4[0]); split_bf16(xv.y, h4[1], l4[1]);
        split_bf16(xv.z, h4[2], l4[2]); split_bf16(xv.w, h4[3], l4[3]);
        uint2 ph = { (uint)h4[0] | ((uint)h4[1] << 16), (uint)h4[2] | ((uint)h4[3] << 16) };
        uint2 pl = { (uint)l4[0] | ((uint)l4[1] << 16), (uint)l4[2] | ((uint)l4[3] << 16) };
        *(uint2*)(sm.aHi + row * 264 + c) = ph;
        *(uint2*)(sm.aLo + row * 264 + c) = pl;
    }
    __syncthreads();
    int aoff = lr * 264 + quad * 8;
    // stage 1: mlp1 + gelu
    {
        const uint4* H4 = (const uint4*)(Whi + 0 * 65536);
        const uint4* L4 = (const uint4*)(Wlo + 0 * 65536);
        f32x4 acc[2] = {};
        #pragma unroll
        for (int ks = 0; ks < 8; ++ks) {
            short8 a_h = lds_frag(sm.aHi + aoff + ks * 32);
            short8 a_l = lds_frag(sm.aLo + aoff + ks * 32);
            #pragma unroll
            for (int ti = 0; ti < 2; ++ti) {
                int off = ((w * 2 + ti) * 8 + ks) * 64 + lane;
                V8 bh, bl; bh.u = H4[off]; bl.u = L4[off];
                acc[ti] = __builtin_amdgcn_mfma_f32_16x16x32_bf16(a_h, bh.s, acc[ti], 0, 0, 0);
                acc[ti] = __builtin_amdgcn_mfma_f32_16x16x32_bf16(a_l, bh.s, acc[ti], 0, 0, 0);
                acc[ti] = __builtin_amdgcn_mfma_f32_16x16x32_bf16(a_h, bl.s, acc[ti], 0, 0, 0);
            }
        }
        #pragma unroll
        for (int ti = 0; ti < 2; ++ti) {
            int n0 = (w * 2 + ti) * 16 + lr;
            float bb = b1[n0];
            #pragma unroll
            for (int r = 0; r < 4; ++r) {
                float o = gelu_f(acc[ti][r] + bb);
                ushort hh, ll; split_bf16(o, hh, ll);
                int ad = (quad * 4 + r) * 264 + n0;
                sm.bHi[ad] = hh; sm.bLo[ad] = ll;
            }
        }
    }
    __syncthreads();
    // stage 2: mlp2
    {
        const uint4* H4 = (const uint4*)(Whi + 1 * 65536);
        const uint4* L4 = (const uint4*)(Wlo + 1 * 65536);
        f32x4 acc[2] = {};
        #pragma unroll
        for (int ks = 0; ks < 8; ++ks) {
            short8 a_h = lds_frag(sm.bHi + aoff + ks * 32);
            short8 a_l = lds_frag(sm.bLo + aoff + ks * 32);
            #pragma unroll
            for (int ti = 0; ti < 2; ++ti) {
                int off = ((w * 2 + ti) * 8 + ks) * 64 + lane;
                V8 bh, bl; bh.u = H4[off]; bl.u = L4[off];
                acc[ti] = __builtin_amdgcn_mfma_f32_16x16x32_bf16(a_h, bh.s, acc[ti], 0, 0, 0);
                acc[ti] = __builtin_amdgcn_mfma_f32_16x16x32_bf16(a_l, bh.s, acc[ti], 0, 0, 0);
                acc[ti] = __builtin_amdgcn_mfma_f32_16x16x32_bf16(a_h, bl.s, acc[ti], 0, 0, 0);
            }
        }
        __syncthreads();
        #pragma unroll
        for (int ti = 0; ti < 2; ++ti) {
            int n0 = (w * 2 + ti) * 16 + lr;
            float bb = b2[n0];
            #pragma unroll
            for (int r = 0; r < 4; ++r) {
                float o = acc[ti][r] + bb;
                ushort hh, ll; split_bf16(o, hh, ll);
                int ad = (quad * 4 + r) * 264 + n0;
                sm.aHi[ad] = hh; sm.aLo[ad] = ll;
            }
        }
    }
    __syncthreads();
    // stage 3: qkv -> bf16 global, per-head layouts (V pre-transposed)
    {
        const uint4* Hq = (const uint4*)(Whi + 2 * 65536);
        const uint4* Lq = (const uint4*)(Wlo + 2 * 65536);
        const uint4* Hk = (const uint4*)(Whi + 3 * 65536);
        const uint4* Lk = (const uint4*)(Wlo + 3 * 65536);
        const uint4* Hv = (const uint4*)(Whi + 4 * 65536);
        const uint4* Lv = (const uint4*)(Wlo + 4 * 65536);
        f32x4 aq[2] = {}, ak[2] = {}, av[2] = {};
        #pragma unroll 2
        for (int ks = 0; ks < 8; ++ks) {
            short8 a_h = lds_frag(sm.aHi + aoff + ks * 32);
            short8 a_l = lds_frag(sm.aLo + aoff + ks * 32);
            #pragma unroll
            for (int ti = 0; ti < 2; ++ti) {
                int off = ((w * 2 + ti) * 8 + ks) * 64 + lane;
                V8 qh, ql, kh, kl, vh, vl;
                qh.u = Hq[off]; ql.u = Lq[off];
                kh.u = Hk[off]; kl.u = Lk[off];
                vh.u = Hv[off]; vl.u = Lv[off];
                aq[ti] = __builtin_amdgcn_mfma_f32_16x16x32_bf16(a_h, qh.s, aq[ti], 0, 0, 0);
                aq[ti] = __builtin_amdgcn_mfma_f32_16x16x32_bf16(a_l, qh.s, aq[ti], 0, 0, 0);
                aq[ti] = __builtin_amdgcn_mfma_f32_16x16x32_bf16(a_h, ql.s, aq[ti], 0, 0, 0);
                ak[ti] = __builtin_amdgcn_mfma_f32_16x16x32_bf16(a_h, kh.s, ak[ti], 0, 0, 0);
                ak[ti] = __builtin_amdgcn_mfma_f32_16x16x32_bf16(a_l, kh.s, ak[ti], 0, 0, 0);
                ak[ti] = __builtin_amdgcn_mfma_f32_16x16x32_bf16(a_h, kl.s, ak[ti], 0, 0, 0);
                av[ti] = __builtin_amdgcn_mfma_f32_16x16x32_bf16(a_h, vh.s, av[ti], 0, 0, 0);
                av[ti] = __builtin_amdgcn_mfma_f32_16x16x32_bf16(a_l, vh.s, av[ti], 0, 0, 0);
                av[ti] = __builtin_amdgcn_mfma_f32_16x16x32_bf16(a_h, vl.s, av[ti], 0, 0, 0);
            }
        }
        #pragma unroll
        for (int ti = 0; ti < 2; ++ti) {
            int n0 = (w * 2 + ti) * 16 + lr;
            int hh = n0 >> 5, dk = n0 & 31;
            float vbq = Bq[n0], vbk = Bk[n0], vbv = Bv[n0];
            #pragma unroll
            for (int r = 0; r < 4; ++r) {
                int row = r0 + quad * 4 + r;
                int bb = row >> 7, n = row & 127;
                int bh_ = bb * 8 + hh;
                Qn[(bh_ * 128 + n) * 32 + dk] = bf16bits(aq[ti][r] + vbq);
                Kn[(bh_ * 128 + n) * 32 + dk] = bf16bits(ak[ti][r] + vbk);
                Vt[(bh_ * 32 + dk) * 128 + n] = bf16bits(av[ti][r] + vbv);
            }
        }
    }
}

// ---------------------------------------------------------------------------
// Dispatch 3: conn (32i x 16j tiles). 256 blocks x 512 thr.
// ---------------------------------------------------------------------------
__global__ __launch_bounds__(512) void k_conn(
    const float* __restrict__ A, const float* __restrict__ Bmat,
    const float* __restrict__ fc_out_b, const float* __restrict__ fc_cat_w,
    const float* __restrict__ fc_cat_b, const float* __restrict__ gumbel_u,
    ushort* __restrict__ maskb) {
    __shared__ __align__(16) float sA[16 * 260], sB[32 * 260];
    int bx = blockIdx.x, t = threadIdx.x;
    int h = bx >> 5;
    int rem = bx & 31;
    int it = rem >> 3, jt = rem & 7;    // it 0..3, jt 0..7
    int i0 = it * 32, j0 = jt * 16;
    int jl = t & 15, il = t >> 4;       // jl 0..15, il 0..31
    #pragma unroll
    for (int p = 0; p < 6; ++p) {
        int id2 = p * 512 + t;          // 0..3071
        if (id2 < 1024) {
            int rr = id2 >> 6, c = (id2 & 63) * 4;
            *(float4*)(sA + rr * 260 + c) =
                *(const float4*)(A + (h * 128 + j0 + rr) * 256 + c);
        } else {
            int id3 = id2 - 1024;
            int rr = id3 >> 6, c = (id3 & 63) * 4;
            float4 bv = *(const float4*)(Bmat + (h * 128 + i0 + rr) * 256 + c);
            float4 fb = *(const float4*)(fc_out_b + c);
            bv.x += fb.x; bv.y += fb.y; bv.z += fb.z; bv.w += fb.w;
            *(float4*)(sB + rr * 260 + c) = bv;
        }
    }
    __syncthreads();
    const float* Ar = sA + jl * 260;
    const float* Br = sB + il * 260;
    float l0 = fc_cat_b[0], l1 = fc_cat_b[1];
    #pragma unroll 4
    for (int d4 = 0; d4 < 64; ++d4) {
        int d = d4 * 4;
        float4 av = *(const float4*)(Ar + d);
        float4 bv = *(const float4*)(Br + d);
        float4 cwA = *(const float4*)(fc_cat_w + d * 2);
        float4 cwB = *(const float4*)(fc_cat_w + d * 2 + 4);
        float h0 = fmaxf(av.x + bv.x, 0.f);
        float h1 = fmaxf(av.y + bv.y, 0.f);
        float h2 = fmaxf(av.z + bv.z, 0.f);
        float h3 = fmaxf(av.w + bv.w, 0.f);
        l0 += h0 * cwA.x + h1 * cwA.z + h2 * cwB.x + h3 * cwB.z;
        l1 += h0 * cwA.y + h1 * cwA.w + h2 * cwB.y + h3 * cwB.w;
    }
    int i = i0 + il, j = j0 + jl;
    float2 uu = *(const float2*)(gumbel_u + ((h * 128 + i) * 128 + j) * 2);
    float g0 = -logf(-logf(uu.x + 1e-10f) + 1e-10f);
    float g1 = -logf(-logf(uu.y + 1e-10f) + 1e-10f);
    bool on = (l1 + g1) > (l0 + g0);
    maskb[(h * 128 + i) * 128 + j] = bf16bits(on ? 0.f : -1e9f);
}

// ---------------------------------------------------------------------------
// Dispatch 4: MFMA attention. 256 blocks x 512 thr, 2 independent jobs per
// block (thread halves). Per-head Q/K coalesced; V pre-transposed in global
// (no LDS V stage, no __syncthreads). Output bf16 hi/lo for LDS-free P5.
// ---------------------------------------------------------------------------
__global__ __launch_bounds__(512) void k_attn_mfma(
    const ushort* __restrict__ Qn, const ushort* __restrict__ Kn,
    const ushort* __restrict__ Vt, const ushort* __restrict__ maskb,
    ushort* __restrict__ aoHi, ushort* __restrict__ aoLo) {
    __shared__ __align__(16) ushort ps[2][64 * 136];
    int bx = blockIdx.x, t = threadIdx.x;
    int lane = t & 63, w = t >> 6, lr = lane & 15, quad = lane >> 4;
    int jh = t >> 8;                     // 0/1: independent 256-thr jobs
    int job = bx * 2 + jh;               // 0..511
    int b = job >> 4, h = (job >> 1) & 7, rh = job & 1;
    int w4 = w & 3;
    int rt = rh * 4 + w4;
    int bh_ = b * 8 + h;
    ushort* psj = ps[jh];
    V8 af;
    af.u = *(const uint4*)(Qn + (bh_ * 128 + rt * 16 + lr) * 32 + quad * 8);
    f32x4 s[8];
    #pragma unroll
    for (int ct = 0; ct < 8; ++ct) {
        V8 bf_;
        bf_.u = *(const uint4*)(Kn + (bh_ * 128 + ct * 16 + lr) * 32 + quad * 8);
        f32x4 z = {0.f, 0.f, 0.f, 0.f};
        s[ct] = __builtin_amdgcn_mfma_f32_16x16x32_bf16(af.s, bf_.s, z, 0, 0, 0);
    }
    const float scale = 0.17677669529663687f;  // 32^-0.5
    const ushort* mrow = maskb + h * 16384;
    #pragma unroll
    for (int r = 0; r < 4; ++r) {
        int lrow = w4 * 16 + quad * 4 + r;
        int grow = rt * 16 + quad * 4 + r;
        float sv[8];
        float mx = -3.0e38f;
        #pragma unroll
        for (int ct = 0; ct < 8; ++ct) {
            float bias = bits_to_f(mrow[grow * 128 + ct * 16 + lr]);
            sv[ct] = s[ct][r] * scale + bias;
            mx = fmaxf(mx, sv[ct]);
        }
        mx = fmaxf(mx, __shfl_xor(mx, 1));
        mx = fmaxf(mx, __shfl_xor(mx, 2));
        mx = fmaxf(mx, __shfl_xor(mx, 4));
        mx = fmaxf(mx, __shfl_xor(mx, 8));
        float sum = 0.f;
        #pragma unroll
        for (int ct = 0; ct < 8; ++ct) {
            sv[ct] = __expf(sv[ct] - mx);
            sum += sv[ct];
        }
        sum += __shfl_xor(sum, 1);
        sum += __shfl_xor(sum, 2);
        sum += __shfl_xor(sum, 4);
        sum += __shfl_xor(sum, 8);
        float iv = 1.f / sum;
        #pragma unroll
        for (int ct = 0; ct < 8; ++ct)
            psj[lrow * 136 + ct * 16 + lr] = bf16bits(sv[ct] * iv);
    }
    f32x4 o0 = {}, o1 = {};
    #pragma unroll
    for (int kk = 0; kk < 4; ++kk) {
        short8 pa = lds_frag(psj + (w4 * 16 + lr) * 136 + kk * 32 + quad * 8);
        V8 v0, v1;
        v0.u = *(const uint4*)(Vt + (bh_ * 32 + lr) * 128 + kk * 32 + quad * 8);
        v1.u = *(const uint4*)(Vt + (bh_ * 32 + 16 + lr) * 128 + kk * 32 + quad * 8);
        o0 = __builtin_amdgcn_mfma_f32_16x16x32_bf16(pa, v0.s, o0, 0, 0, 0);
        o1 = __builtin_amdgcn_mfma_f32_16x16x32_bf16(pa, v1.s, o1, 0, 0, 0);
    }
    #pragma unroll
    for (int r = 0; r < 4; ++r) {
        int grow = rt * 16 + quad * 4 + r;
        int base = (b * 128 + grow) * 256 + h * 32;
        ushort hh, ll;
        split_bf16(o0[r], hh, ll);
        aoHi[base + lr] = hh; aoLo[base + lr] = ll;
        split_bf16(o1[r], hh, ll);
        aoHi[base + 16 + lr] = hh; aoLo[base + 16 + lr] = ll;
    }
}

// ---------------------------------------------------------------------------
// Dispatch 5: out-proj GEMM, LDS-free (A fragments straight from bf16 hi/lo
// global). 256 blocks x 512 thr; wave w covers col tiles 2w, 2w+1.
// ---------------------------------------------------------------------------
__global__ __launch_bounds__(512) void k_gemm16(
    const ushort* __restrict__ aoHi, const ushort* __restrict__ aoLo,
    const ushort* __restrict__ Whi, const ushort* __restrict__ Wlo,
    const float* __restrict__ bias, float* __restrict__ Y) {
    int t = threadIdx.x;
    int lane = t & 63, w = t >> 6, lr = lane & 15, quad = lane >> 4;
    int r0 = blockIdx.x * 16;
    const uint4* H4 = (const uint4*)Whi;
    const uint4* L4 = (const uint4*)Wlo;
    f32x4 acc[2] = {};
    #pragma unroll
    for (int ks = 0; ks < 8; ++ks) {
        V8 ahv, alv;
        ahv.u = *(const uint4*)(aoHi + (r0 + lr) * 256 + ks * 32 + quad * 8);
        alv.u = *(const uint4*)(aoLo + (r0 + lr) * 256 + ks * 32 + quad * 8);
        #pragma unroll
        for (int ti = 0; ti < 2; ++ti) {
            int off = ((w * 2 + ti) * 8 + ks) * 64 + lane;
            V8 bh, bl; bh.u = H4[off]; bl.u = L4[off];
            acc[ti] = __builtin_amdgcn_mfma_f32_16x16x32_bf16(ahv.s, bh.s, acc[ti], 0, 0, 0);
            acc[ti] = __builtin_amdgcn_mfma_f32_16x16x32_bf16(alv.s, bh.s, acc[ti], 0, 0, 0);
            acc[ti] = __builtin_amdgcn_mfma_f32_16x16x32_bf16(ahv.s, bl.s, acc[ti], 0, 0, 0);
        }
    }
    #pragma unroll
    for (int ti = 0; ti < 2; ++ti) {
        int n0 = (w * 2 + ti) * 16 + lr;
        float bs = bias[n0];
        #pragma unroll
        for (int r = 0; r < 4; ++r)
            Y[(r0 + quad * 4 + r) * 256 + n0] = acc[ti][r] + bs;
    }
}

// ---------------------------------------------------------------------------
extern "C" void kernel_launch(void* const* d_in, const int* in_sizes, int n_in,
                              void* d_out, int out_size, void* d_ws, size_t ws_size,
                              hipStream_t stream) {
    const float* x        = (const float*)d_in[0];
    const float* gumbel_u = (const float*)d_in[1];
    const float* memory_w = (const float*)d_in[2];
    const float* fc_out_w = (const float*)d_in[3];
    const float* fc_out_b = (const float*)d_in[4];
    const float* fc_cat_w = (const float*)d_in[5];
    const float* fc_cat_b = (const float*)d_in[6];
    const float* wq       = (const float*)d_in[7];
    const float* bq       = (const float*)d_in[8];
    const float* wk       = (const float*)d_in[9];
    const float* bk       = (const float*)d_in[10];
    const float* wv_      = (const float*)d_in[11];
    const float* bv_      = (const float*)d_in[12];
    const float* out_w    = (const float*)d_in[13];
    const float* out_b    = (const float*)d_in[14];
    const float* mlp_w1   = (const float*)d_in[15];
    const float* mlp_b1   = (const float*)d_in[16];
    const float* mlp_w2   = (const float*)d_in[17];
    const float* mlp_b2   = (const float*)d_in[18];

    // Workspace (float offsets).
    float* ws     = (float*)d_ws;
    float* A      = ws;                        //        0 .. 262144
    float* Bm     = ws + 262144;               //   262144 .. 524288
    ushort* mask  = (ushort*)(ws + 524288);    //   524288 .. 557056 (65536 u16)
    ushort* qn    = (ushort*)(ws + 589824);    //   589824 .. 1114112
    ushort* kn    = (ushort*)(ws + 1114112);   //  1114112 .. 1638400
    ushort* vt    = (ushort*)(ws + 1638400);   //  1638400 .. 2162688
    ushort* aoHi  = (ushort*)(ws + 2162688);   //  2162688 .. 2686976
    ushort* aoLo  = (ushort*)(ws + 2686976);   //  2686976 .. 3211264
    ushort* wf_hi = (ushort*)(ws + 3211264);   //  3211264 .. 3473408
    ushort* wf_lo = wf_hi + 8 * 65536;         //  3473408 .. 3735552
    float* out    = (float*)d_out;

    // DAG: wprep -> p2(featproj+fused3) -> conn -> attn -> gemm16.
    k_wprep<<<dim3(128), dim3(512), 0, stream>>>(
        mlp_w1, mlp_w2, wq, wk, wv_, out_w, fc_out_w, wf_hi, wf_lo);
    k_p2<<<dim3(256), dim3(512), 0, stream>>>(
        memory_w, x, wf_hi, wf_lo, mlp_b1, mlp_b2, bq, bk, bv_,
        A, Bm, qn, kn, vt);
    k_conn<<<dim3(256), dim3(512), 0, stream>>>(
        A, Bm, fc_out_b, fc_cat_w, fc_cat_b, gumbel_u, mask);
    k_attn_mfma<<<dim3(256), dim3(512), 0, stream>>>(qn, kn, vt, mask, aoHi, aoLo);
    k_gemm16<<<dim3(256), dim3(512), 0, stream>>>(aoHi, aoLo, wf_hi + 5 * 65536,
                                                  wf_lo + 5 * 65536, out_b, out);
}

// Round 4
// 150.739 us; speedup vs baseline: 1.9623x; 1.0276x over previous
//
#include <hip/hip_runtime.h>
#include <hip/hip_bf16.h>
#include <math.h>

// Problem constants: H=8, d_model=256, N=128, d_k=32, B=32, rows=4096

typedef short short8 __attribute__((ext_vector_type(8)));
typedef float f32x4 __attribute__((ext_vector_type(4)));

union V8 { uint4 u; short8 s; };

__device__ __forceinline__ float gelu_f(float x) {
    float inner = 0.7978845608028654f * (x + 0.044715f * x * x * x);
    return 0.5f * x * (1.0f + tanhf(inner));
}
__device__ __forceinline__ void split_bf16(float x, ushort& h, ushort& l) {
    __hip_bfloat16 bh = __float2bfloat16(x);          // RN
    float hf = __bfloat162float(bh);
    __hip_bfloat16 bl = __float2bfloat16(x - hf);
    h = __builtin_bit_cast(ushort, bh);
    l = __builtin_bit_cast(ushort, bl);
}
__device__ __forceinline__ ushort bf16bits(float x) {
    return __builtin_bit_cast(ushort, __float2bfloat16(x));
}
__device__ __forceinline__ float bits_to_f(ushort v) {
    return __builtin_bit_cast(float, ((uint)v) << 16);
}
__device__ __forceinline__ short8 lds_frag(const ushort* p) {
    V8 v; v.u = *(const uint4*)p; return v.s;
}

// Frag layout for all prepped weights: elem (k,n) of mat m lives at
//   m*65536 + ((tg*8+ks)*64 + lane)*8 + j
// with tg=n>>4, lr=n&15, ks=k>>5, quad=(k>>3)&3, j=k&7, lane=quad*16+lr.
// Mats: 0=mlp_w1 1=mlp_w2 2=wq 3=wk 4=wv 5=out_w 6=fc_out_w[0:256] 7=[256:512]

// ---------------------------------------------------------------------------
// Dispatch 1: wprep only (64 blocks x 512 thr, two 256-thr jobs per block).
// MUST be its own dispatch: featproj/fused3 read its output.
// ---------------------------------------------------------------------------
__global__ __launch_bounds__(512) void k_wprep(
    const float* __restrict__ mlp_w1, const float* __restrict__ mlp_w2,
    const float* __restrict__ wq, const float* __restrict__ wk,
    const float* __restrict__ wv, const float* __restrict__ out_w,
    const float* __restrict__ fc_out_w,
    ushort* __restrict__ hi, ushort* __restrict__ lo) {
    __shared__ __align__(16) float xs2[2][32 * 132];
    int bx = blockIdx.x, t = threadIdx.x;
    int half = t >> 8, tl = t & 255;
    int job = bx * 2 + half;                      // 0..127
    int m = job >> 4, ks = (job >> 1) & 7, nh = job & 1;
    const float* W = m == 0 ? mlp_w1 : m == 1 ? mlp_w2 : m == 2 ? wq :
                     m == 3 ? wk : m == 4 ? wv : m == 5 ? out_w :
                     m == 6 ? fc_out_w : fc_out_w + 65536;
    ushort* Hm = hi + m * 65536;
    ushort* Lm = lo + m * 65536;
    float* xs = xs2[half];
    #pragma unroll
    for (int p = 0; p < 4; ++p) {
        int idx = p * 256 + tl;
        int row = idx >> 5, c4 = (idx & 31) * 4;
        *(float4*)(xs + row * 132 + c4) =
            *(const float4*)(W + (ks * 32 + row) * 256 + nh * 128 + c4);
    }
    __syncthreads();
    int lane = tl & 63, lr = lane & 15, quad = lane >> 4;
    #pragma unroll
    for (int it = 0; it < 2; ++it) {
        int tgl = (tl >> 6) + 4 * it;
        int tg = nh * 8 + tgl;
        int nl = tgl * 16 + lr;
        ushort hb[8], lb[8];
        #pragma unroll
        for (int j = 0; j < 8; ++j)
            split_bf16(xs[(quad * 8 + j) * 132 + nl], hb[j], lb[j]);
        uint4 ph = { (uint)hb[0] | ((uint)hb[1] << 16), (uint)hb[2] | ((uint)hb[3] << 16),
                     (uint)hb[4] | ((uint)hb[5] << 16), (uint)hb[6] | ((uint)hb[7] << 16) };
        uint4 pl = { (uint)lb[0] | ((uint)lb[1] << 16), (uint)lb[2] | ((uint)lb[3] << 16),
                     (uint)lb[4] | ((uint)lb[5] << 16), (uint)lb[6] | ((uint)lb[7] << 16) };
        int idx = ((tg * 8 + ks) * 64 + lane) * 8;
        *(uint4*)(Hm + idx) = ph;
        *(uint4*)(Lm + idx) = pl;
    }
}

// ---------------------------------------------------------------------------
// Dispatch 2: blocks 0..63 = featproj (stage once, 8 waves cover all jobs);
//             blocks 64..319 = fused3 (mlp1->mlp2->qkv, per-head bf16 out,
//             V pre-transposed). Both only READ wf_hi/wf_lo. 512 threads.
// ---------------------------------------------------------------------------
__global__ __launch_bounds__(512) void k_p2(
    const float* __restrict__ memory_w, const float* __restrict__ X,
    const ushort* __restrict__ Whi, const ushort* __restrict__ Wlo,
    const float* __restrict__ b1, const float* __restrict__ b2,
    const float* __restrict__ Bq, const float* __restrict__ Bk,
    const float* __restrict__ Bv,
    float* __restrict__ A, float* __restrict__ Bm,
    ushort* __restrict__ Qn, ushort* __restrict__ Kn, ushort* __restrict__ Vt) {
    __shared__ __align__(16) union {
        struct { ushort xhi[16 * 264], xlo[16 * 264]; } f;   // featproj 16.9 KB
        struct {
            ushort aHi[16 * 264], aLo[16 * 264];
            ushort bHi[16 * 264], bLo[16 * 264];
        } g;                                                  // fused3 33.8 KB
    } sm;
    int bx = blockIdx.x, t = threadIdx.x;
    if (bx < 64) {
        // ---- featproj: rt = bx; one staged tile serves all 8 (msel,cq)
        int rt = bx;
        #pragma unroll
        for (int ii = 0; ii < 2; ++ii) {
            int f4 = ii * 512 + t;
            int rr = f4 >> 6, c = (f4 & 63) * 4;
            int r = rt * 16 + rr;
            int h = r >> 7, n = r & 127;
            float4 xv = *(const float4*)(memory_w + n * 2048 + h * 256 + c);
            ushort hh[4], ll[4];
            split_bf16(xv.x, hh[0], ll[0]); split_bf16(xv.y, hh[1], ll[1]);
            split_bf16(xv.z, hh[2], ll[2]); split_bf16(xv.w, hh[3], ll[3]);
            uint2 ph = { (uint)hh[0] | ((uint)hh[1] << 16), (uint)hh[2] | ((uint)hh[3] << 16) };
            uint2 pl = { (uint)ll[0] | ((uint)ll[1] << 16), (uint)ll[2] | ((uint)ll[3] << 16) };
            *(uint2*)(sm.f.xhi + rr * 264 + c) = ph;
            *(uint2*)(sm.f.xlo + rr * 264 + c) = pl;
        }
        __syncthreads();
        int lane = t & 63, w = t >> 6;
        int lr = lane & 15, quad = lane >> 4;
        int msel = w & 1, cq = w >> 1;
        const uint4* H4 = (const uint4*)(Whi + (6 + msel) * 65536);
        const uint4* L4 = (const uint4*)(Wlo + (6 + msel) * 65536);
        const ushort* ah = sm.f.xhi + lr * 264 + quad * 8;
        const ushort* al = sm.f.xlo + lr * 264 + quad * 8;
        float* O = msel ? Bm : A;
        #pragma unroll
        for (int i = 0; i < 4; ++i) {
            int tg = cq * 4 + i;
            f32x4 acc = {};
            #pragma unroll
            for (int ks = 0; ks < 8; ++ks) {
                short8 a_h = lds_frag(ah + ks * 32);
                short8 a_l = lds_frag(al + ks * 32);
                int off = (tg * 8 + ks) * 64 + lane;
                V8 bh, bl; bh.u = H4[off]; bl.u = L4[off];
                acc = __builtin_amdgcn_mfma_f32_16x16x32_bf16(a_h, bh.s, acc, 0, 0, 0);
                acc = __builtin_amdgcn_mfma_f32_16x16x32_bf16(a_l, bh.s, acc, 0, 0, 0);
                acc = __builtin_amdgcn_mfma_f32_16x16x32_bf16(a_h, bl.s, acc, 0, 0, 0);
            }
            int n0 = tg * 16 + lr;
            #pragma unroll
            for (int r = 0; r < 4; ++r)
                O[(rt * 16 + quad * 4 + r) * 256 + n0] = acc[r];
        }
        return;
    }
    // ================= fused3 =================
    int r0 = (bx - 64) * 16;
    int lane = t & 63, w = t >> 6, lr = lane & 15, quad = lane >> 4;
    #pragma unroll
    for (int ii = 0; ii < 2; ++ii) {
        int f4 = ii * 512 + t;
        int row = f4 >> 6, c = (f4 & 63) * 4;
        float4 xv = *(const float4*)(X + (r0 + row) * 256 + c);
        ushort h4[4], l4[4];
        split_bf16(xv.x, h4[0], l4[0]); split_bf16(xv.y, h4[1], l4[1]);
        split_bf16(xv.z, h4[2], l4[2]); split_bf16(xv.w, h4[3], l4[3]);
        uint2 ph = { (uint)h4[0] | ((uint)h4[1] << 16), (uint)h4[2] | ((uint)h4[3] << 16) };
        uint2 pl = { (uint)l4[0] | ((uint)l4[1] << 16), (uint)l4[2] | ((uint)l4[3] << 16) };
        *(uint2*)(sm.g.aHi + row * 264 + c) = ph;
        *(uint2*)(sm.g.aLo + row * 264 + c) = pl;
    }
    __syncthreads();
    int aoff = lr * 264 + quad * 8;
    // stage 1: mlp1 + gelu
    {
        const uint4* H4 = (const uint4*)(Whi + 0 * 65536);
        const uint4* L4 = (const uint4*)(Wlo + 0 * 65536);
        f32x4 acc[2] = {};
        #pragma unroll
        for (int ks = 0; ks < 8; ++ks) {
            short8 a_h = lds_frag(sm.g.aHi + aoff + ks * 32);
            short8 a_l = lds_frag(sm.g.aLo + aoff + ks * 32);
            #pragma unroll
            for (int ti = 0; ti < 2; ++ti) {
                int off = ((w * 2 + ti) * 8 + ks) * 64 + lane;
                V8 bh, bl; bh.u = H4[off]; bl.u = L4[off];
                acc[ti] = __builtin_amdgcn_mfma_f32_16x16x32_bf16(a_h, bh.s, acc[ti], 0, 0, 0);
                acc[ti] = __builtin_amdgcn_mfma_f32_16x16x32_bf16(a_l, bh.s, acc[ti], 0, 0, 0);
                acc[ti] = __builtin_amdgcn_mfma_f32_16x16x32_bf16(a_h, bl.s, acc[ti], 0, 0, 0);
            }
        }
        #pragma unroll
        for (int ti = 0; ti < 2; ++ti) {
            int n0 = (w * 2 + ti) * 16 + lr;
            float bb = b1[n0];
            #pragma unroll
            for (int r = 0; r < 4; ++r) {
                float o = gelu_f(acc[ti][r] + bb);
                ushort hh, ll; split_bf16(o, hh, ll);
                int ad = (quad * 4 + r) * 264 + n0;
                sm.g.bHi[ad] = hh; sm.g.bLo[ad] = ll;
            }
        }
    }
    __syncthreads();
    // stage 2: mlp2
    {
        const uint4* H4 = (const uint4*)(Whi + 1 * 65536);
        const uint4* L4 = (const uint4*)(Wlo + 1 * 65536);
        f32x4 acc[2] = {};
        #pragma unroll
        for (int ks = 0; ks < 8; ++ks) {
            short8 a_h = lds_frag(sm.g.bHi + aoff + ks * 32);
            short8 a_l = lds_frag(sm.g.bLo + aoff + ks * 32);
            #pragma unroll
            for (int ti = 0; ti < 2; ++ti) {
                int off = ((w * 2 + ti) * 8 + ks) * 64 + lane;
                V8 bh, bl; bh.u = H4[off]; bl.u = L4[off];
                acc[ti] = __builtin_amdgcn_mfma_f32_16x16x32_bf16(a_h, bh.s, acc[ti], 0, 0, 0);
                acc[ti] = __builtin_amdgcn_mfma_f32_16x16x32_bf16(a_l, bh.s, acc[ti], 0, 0, 0);
                acc[ti] = __builtin_amdgcn_mfma_f32_16x16x32_bf16(a_h, bl.s, acc[ti], 0, 0, 0);
            }
        }
        __syncthreads();
        #pragma unroll
        for (int ti = 0; ti < 2; ++ti) {
            int n0 = (w * 2 + ti) * 16 + lr;
            float bb = b2[n0];
            #pragma unroll
            for (int r = 0; r < 4; ++r) {
                float o = acc[ti][r] + bb;
                ushort hh, ll; split_bf16(o, hh, ll);
                int ad = (quad * 4 + r) * 264 + n0;
                sm.g.aHi[ad] = hh; sm.g.aLo[ad] = ll;
            }
        }
    }
    __syncthreads();
    // stage 3: qkv -> bf16 global, per-head layouts (V pre-transposed)
    {
        const uint4* Hq = (const uint4*)(Whi + 2 * 65536);
        const uint4* Lq = (const uint4*)(Wlo + 2 * 65536);
        const uint4* Hk = (const uint4*)(Whi + 3 * 65536);
        const uint4* Lk = (const uint4*)(Wlo + 3 * 65536);
        const uint4* Hv = (const uint4*)(Whi + 4 * 65536);
        const uint4* Lv = (const uint4*)(Wlo + 4 * 65536);
        f32x4 aq[2] = {}, ak[2] = {}, av[2] = {};
        #pragma unroll 2
        for (int ks = 0; ks < 8; ++ks) {
            short8 a_h = lds_frag(sm.g.aHi + aoff + ks * 32);
            short8 a_l = lds_frag(sm.g.aLo + aoff + ks * 32);
            #pragma unroll
            for (int ti = 0; ti < 2; ++ti) {
                int off = ((w * 2 + ti) * 8 + ks) * 64 + lane;
                V8 qh, ql, kh, kl, vh, vl;
                qh.u = Hq[off]; ql.u = Lq[off];
                kh.u = Hk[off]; kl.u = Lk[off];
                vh.u = Hv[off]; vl.u = Lv[off];
                aq[ti] = __builtin_amdgcn_mfma_f32_16x16x32_bf16(a_h, qh.s, aq[ti], 0, 0, 0);
                aq[ti] = __builtin_amdgcn_mfma_f32_16x16x32_bf16(a_l, qh.s, aq[ti], 0, 0, 0);
                aq[ti] = __builtin_amdgcn_mfma_f32_16x16x32_bf16(a_h, ql.s, aq[ti], 0, 0, 0);
                ak[ti] = __builtin_amdgcn_mfma_f32_16x16x32_bf16(a_h, kh.s, ak[ti], 0, 0, 0);
                ak[ti] = __builtin_amdgcn_mfma_f32_16x16x32_bf16(a_l, kh.s, ak[ti], 0, 0, 0);
                ak[ti] = __builtin_amdgcn_mfma_f32_16x16x32_bf16(a_h, kl.s, ak[ti], 0, 0, 0);
                av[ti] = __builtin_amdgcn_mfma_f32_16x16x32_bf16(a_h, vh.s, av[ti], 0, 0, 0);
                av[ti] = __builtin_amdgcn_mfma_f32_16x16x32_bf16(a_l, vh.s, av[ti], 0, 0, 0);
                av[ti] = __builtin_amdgcn_mfma_f32_16x16x32_bf16(a_h, vl.s, av[ti], 0, 0, 0);
            }
        }
        #pragma unroll
        for (int ti = 0; ti < 2; ++ti) {
            int n0 = (w * 2 + ti) * 16 + lr;
            int hh = n0 >> 5, dk = n0 & 31;
            float vbq = Bq[n0], vbk = Bk[n0], vbv = Bv[n0];
            #pragma unroll
            for (int r = 0; r < 4; ++r) {
                int row = r0 + quad * 4 + r;
                int bb = row >> 7, n = row & 127;
                int bh_ = bb * 8 + hh;
                Qn[(bh_ * 128 + n) * 32 + dk] = bf16bits(aq[ti][r] + vbq);
                Kn[(bh_ * 128 + n) * 32 + dk] = bf16bits(ak[ti][r] + vbk);
                Vt[(bh_ * 32 + dk) * 128 + n] = bf16bits(av[ti][r] + vbv);
            }
        }
    }
}

// ---------------------------------------------------------------------------
// Dispatch 3: conn (32i x 16j tiles). 256 blocks x 512 thr.
// ---------------------------------------------------------------------------
__global__ __launch_bounds__(512) void k_conn(
    const float* __restrict__ A, const float* __restrict__ Bmat,
    const float* __restrict__ fc_out_b, const float* __restrict__ fc_cat_w,
    const float* __restrict__ fc_cat_b, const float* __restrict__ gumbel_u,
    ushort* __restrict__ maskb) {
    __shared__ __align__(16) float sA[16 * 260], sB[32 * 260];
    int bx = blockIdx.x, t = threadIdx.x;
    int h = bx >> 5;
    int rem = bx & 31;
    int it = rem >> 3, jt = rem & 7;    // it 0..3, jt 0..7
    int i0 = it * 32, j0 = jt * 16;
    int jl = t & 15, il = t >> 4;       // jl 0..15, il 0..31
    #pragma unroll
    for (int p = 0; p < 6; ++p) {
        int id2 = p * 512 + t;          // 0..3071
        if (id2 < 1024) {
            int rr = id2 >> 6, c = (id2 & 63) * 4;
            *(float4*)(sA + rr * 260 + c) =
                *(const float4*)(A + (h * 128 + j0 + rr) * 256 + c);
        } else {
            int id3 = id2 - 1024;
            int rr = id3 >> 6, c = (id3 & 63) * 4;
            float4 bv = *(const float4*)(Bmat + (h * 128 + i0 + rr) * 256 + c);
            float4 fb = *(const float4*)(fc_out_b + c);
            bv.x += fb.x; bv.y += fb.y; bv.z += fb.z; bv.w += fb.w;
            *(float4*)(sB + rr * 260 + c) = bv;
        }
    }
    __syncthreads();
    const float* Ar = sA + jl * 260;
    const float* Br = sB + il * 260;
    float l0 = fc_cat_b[0], l1 = fc_cat_b[1];
    #pragma unroll 4
    for (int d4 = 0; d4 < 64; ++d4) {
        int d = d4 * 4;
        float4 av = *(const float4*)(Ar + d);
        float4 bv = *(const float4*)(Br + d);
        float4 cwA = *(const float4*)(fc_cat_w + d * 2);
        float4 cwB = *(const float4*)(fc_cat_w + d * 2 + 4);
        float h0 = fmaxf(av.x + bv.x, 0.f);
        float h1 = fmaxf(av.y + bv.y, 0.f);
        float h2 = fmaxf(av.z + bv.z, 0.f);
        float h3 = fmaxf(av.w + bv.w, 0.f);
        l0 += h0 * cwA.x + h1 * cwA.z + h2 * cwB.x + h3 * cwB.z;
        l1 += h0 * cwA.y + h1 * cwA.w + h2 * cwB.y + h3 * cwB.w;
    }
    int i = i0 + il, j = j0 + jl;
    float2 uu = *(const float2*)(gumbel_u + ((h * 128 + i) * 128 + j) * 2);
    float g0 = -logf(-logf(uu.x + 1e-10f) + 1e-10f);
    float g1 = -logf(-logf(uu.y + 1e-10f) + 1e-10f);
    bool on = (l1 + g1) > (l0 + g0);
    maskb[(h * 128 + i) * 128 + j] = bf16bits(on ? 0.f : -1e9f);
}

// ---------------------------------------------------------------------------
// Dispatch 4: MFMA attention. 256 blocks x 512 thr, 2 independent jobs per
// block (thread halves). Per-head Q/K coalesced; V pre-transposed in global
// (no LDS V stage, no __syncthreads). Output bf16 hi/lo for LDS-free P5.
// ---------------------------------------------------------------------------
__global__ __launch_bounds__(512) void k_attn_mfma(
    const ushort* __restrict__ Qn, const ushort* __restrict__ Kn,
    const ushort* __restrict__ Vt, const ushort* __restrict__ maskb,
    ushort* __restrict__ aoHi, ushort* __restrict__ aoLo) {
    __shared__ __align__(16) ushort ps[2][64 * 136];
    int bx = blockIdx.x, t = threadIdx.x;
    int lane = t & 63, w = t >> 6, lr = lane & 15, quad = lane >> 4;
    int jh = t >> 8;                     // 0/1: independent 256-thr jobs
    int job = bx * 2 + jh;               // 0..511
    int b = job >> 4, h = (job >> 1) & 7, rh = job & 1;
    int w4 = w & 3;
    int rt = rh * 4 + w4;
    int bh_ = b * 8 + h;
    ushort* psj = ps[jh];
    V8 af;
    af.u = *(const uint4*)(Qn + (bh_ * 128 + rt * 16 + lr) * 32 + quad * 8);
    f32x4 s[8];
    #pragma unroll
    for (int ct = 0; ct < 8; ++ct) {
        V8 bf_;
        bf_.u = *(const uint4*)(Kn + (bh_ * 128 + ct * 16 + lr) * 32 + quad * 8);
        f32x4 z = {0.f, 0.f, 0.f, 0.f};
        s[ct] = __builtin_amdgcn_mfma_f32_16x16x32_bf16(af.s, bf_.s, z, 0, 0, 0);
    }
    const float scale = 0.17677669529663687f;  // 32^-0.5
    const ushort* mrow = maskb + h * 16384;
    #pragma unroll
    for (int r = 0; r < 4; ++r) {
        int lrow = w4 * 16 + quad * 4 + r;
        int grow = rt * 16 + quad * 4 + r;
        float sv[8];
        float mx = -3.0e38f;
        #pragma unroll
        for (int ct = 0; ct < 8; ++ct) {
            float bias = bits_to_f(mrow[grow * 128 + ct * 16 + lr]);
            sv[ct] = s[ct][r] * scale + bias;
            mx = fmaxf(mx, sv[ct]);
        }
        mx = fmaxf(mx, __shfl_xor(mx, 1));
        mx = fmaxf(mx, __shfl_xor(mx, 2));
        mx = fmaxf(mx, __shfl_xor(mx, 4));
        mx = fmaxf(mx, __shfl_xor(mx, 8));
        float sum = 0.f;
        #pragma unroll
        for (int ct = 0; ct < 8; ++ct) {
            sv[ct] = __expf(sv[ct] - mx);
            sum += sv[ct];
        }
        sum += __shfl_xor(sum, 1);
        sum += __shfl_xor(sum, 2);
        sum += __shfl_xor(sum, 4);
        sum += __shfl_xor(sum, 8);
        float iv = 1.f / sum;
        #pragma unroll
        for (int ct = 0; ct < 8; ++ct)
            psj[lrow * 136 + ct * 16 + lr] = bf16bits(sv[ct] * iv);
    }
    f32x4 o0 = {}, o1 = {};
    #pragma unroll
    for (int kk = 0; kk < 4; ++kk) {
        short8 pa = lds_frag(psj + (w4 * 16 + lr) * 136 + kk * 32 + quad * 8);
        V8 v0, v1;
        v0.u = *(const uint4*)(Vt + (bh_ * 32 + lr) * 128 + kk * 32 + quad * 8);
        v1.u = *(const uint4*)(Vt + (bh_ * 32 + 16 + lr) * 128 + kk * 32 + quad * 8);
        o0 = __builtin_amdgcn_mfma_f32_16x16x32_bf16(pa, v0.s, o0, 0, 0, 0);
        o1 = __builtin_amdgcn_mfma_f32_16x16x32_bf16(pa, v1.s, o1, 0, 0, 0);
    }
    #pragma unroll
    for (int r = 0; r < 4; ++r) {
        int grow = rt * 16 + quad * 4 + r;
        int base = (b * 128 + grow) * 256 + h * 32;
        ushort hh, ll;
        split_bf16(o0[r], hh, ll);
        aoHi[base + lr] = hh; aoLo[base + lr] = ll;
        split_bf16(o1[r], hh, ll);
        aoHi[base + 16 + lr] = hh; aoLo[base + 16 + lr] = ll;
    }
}

// ---------------------------------------------------------------------------
// Dispatch 5: out-proj GEMM, LDS-free (A fragments straight from bf16 hi/lo
// global). 256 blocks x 512 thr; wave w covers col tiles 2w, 2w+1.
// ---------------------------------------------------------------------------
__global__ __launch_bounds__(512) void k_gemm16(
    const ushort* __restrict__ aoHi, const ushort* __restrict__ aoLo,
    const ushort* __restrict__ Whi, const ushort* __restrict__ Wlo,
    const float* __restrict__ bias, float* __restrict__ Y) {
    int t = threadIdx.x;
    int lane = t & 63, w = t >> 6, lr = lane & 15, quad = lane >> 4;
    int r0 = blockIdx.x * 16;
    const uint4* H4 = (const uint4*)Whi;
    const uint4* L4 = (const uint4*)Wlo;
    f32x4 acc[2] = {};
    #pragma unroll
    for (int ks = 0; ks < 8; ++ks) {
        V8 ahv, alv;
        ahv.u = *(const uint4*)(aoHi + (r0 + lr) * 256 + ks * 32 + quad * 8);
        alv.u = *(const uint4*)(aoLo + (r0 + lr) * 256 + ks * 32 + quad * 8);
        #pragma unroll
        for (int ti = 0; ti < 2; ++ti) {
            int off = ((w * 2 + ti) * 8 + ks) * 64 + lane;
            V8 bh, bl; bh.u = H4[off]; bl.u = L4[off];
            acc[ti] = __builtin_amdgcn_mfma_f32_16x16x32_bf16(ahv.s, bh.s, acc[ti], 0, 0, 0);
            acc[ti] = __builtin_amdgcn_mfma_f32_16x16x32_bf16(alv.s, bh.s, acc[ti], 0, 0, 0);
            acc[ti] = __builtin_amdgcn_mfma_f32_16x16x32_bf16(ahv.s, bl.s, acc[ti], 0, 0, 0);
        }
    }
    #pragma unroll
    for (int ti = 0; ti < 2; ++ti) {
        int n0 = (w * 2 + ti) * 16 + lr;
        float bs = bias[n0];
        #pragma unroll
        for (int r = 0; r < 4; ++r)
            Y[(r0 + quad * 4 + r) * 256 + n0] = acc[ti][r] + bs;
    }
}

// ---------------------------------------------------------------------------
extern "C" void kernel_launch(void* const* d_in, const int* in_sizes, int n_in,
                              void* d_out, int out_size, void* d_ws, size_t ws_size,
                              hipStream_t stream) {
    const float* x        = (const float*)d_in[0];
    const float* gumbel_u = (const float*)d_in[1];
    const float* memory_w = (const float*)d_in[2];
    const float* fc_out_w = (const float*)d_in[3];
    const float* fc_out_b = (const float*)d_in[4];
    const float* fc_cat_w = (const float*)d_in[5];
    const float* fc_cat_b = (const float*)d_in[6];
    const float* wq       = (const float*)d_in[7];
    const float* bq       = (const float*)d_in[8];
    const float* wk       = (const float*)d_in[9];
    const float* bk       = (const float*)d_in[10];
    const float* wv_      = (const float*)d_in[11];
    const float* bv_      = (const float*)d_in[12];
    const float* out_w    = (const float*)d_in[13];
    const float* out_b    = (const float*)d_in[14];
    const float* mlp_w1   = (const float*)d_in[15];
    const float* mlp_b1   = (const float*)d_in[16];
    const float* mlp_w2   = (const float*)d_in[17];
    const float* mlp_b2   = (const float*)d_in[18];

    // Workspace (float offsets).
    float* ws     = (float*)d_ws;
    float* A      = ws;                        //        0 .. 262144
    float* Bm     = ws + 262144;               //   262144 .. 524288
    ushort* mask  = (ushort*)(ws + 524288);    //   524288 .. 557056 (65536 u16)
    ushort* qn    = (ushort*)(ws + 589824);    //   589824 .. 1114112
    ushort* kn    = (ushort*)(ws + 1114112);   //  1114112 .. 1638400
    ushort* vt    = (ushort*)(ws + 1638400);   //  1638400 .. 2162688
    ushort* aoHi  = (ushort*)(ws + 2162688);   //  2162688 .. 2686976
    ushort* aoLo  = (ushort*)(ws + 2686976);   //  2686976 .. 3211264
    ushort* wf_hi = (ushort*)(ws + 3211264);   //  3211264 .. 3473408
    ushort* wf_lo = wf_hi + 8 * 65536;         //  3473408 .. 3735552
    float* out    = (float*)d_out;

    // DAG: wprep -> p2(featproj||fused3) -> conn -> attn -> gemm16.
    k_wprep<<<dim3(64), dim3(512), 0, stream>>>(
        mlp_w1, mlp_w2, wq, wk, wv_, out_w, fc_out_w, wf_hi, wf_lo);
    k_p2<<<dim3(320), dim3(512), 0, stream>>>(
        memory_w, x, wf_hi, wf_lo, mlp_b1, mlp_b2, bq, bk, bv_,
        A, Bm, qn, kn, vt);
    k_conn<<<dim3(256), dim3(512), 0, stream>>>(
        A, Bm, fc_out_b, fc_cat_w, fc_cat_b, gumbel_u, mask);
    k_attn_mfma<<<dim3(256), dim3(512), 0, stream>>>(qn, kn, vt, mask, aoHi, aoLo);
    k_gemm16<<<dim3(256), dim3(512), 0, stream>>>(aoHi, aoLo, wf_hi + 5 * 65536,
                                                  wf_lo + 5 * 65536, out_b, out);
}

// Round 5
// 146.295 us; speedup vs baseline: 2.0220x; 1.0304x over previous
//
#include <hip/hip_runtime.h>
#include <hip/hip_bf16.h>
#include <math.h>

// Problem constants: H=8, d_model=256, N=128, d_k=32, B=32, rows=4096

typedef short short8 __attribute__((ext_vector_type(8)));
typedef float f32x4 __attribute__((ext_vector_type(4)));

union V8 { uint4 u; short8 s; };

__device__ __forceinline__ float gelu_f(float x) {
    float inner = 0.7978845608028654f * (x + 0.044715f * x * x * x);
    return 0.5f * x * (1.0f + tanhf(inner));
}
__device__ __forceinline__ void split_bf16(float x, ushort& h, ushort& l) {
    __hip_bfloat16 bh = __float2bfloat16(x);          // RN
    float hf = __bfloat162float(bh);
    __hip_bfloat16 bl = __float2bfloat16(x - hf);
    h = __builtin_bit_cast(ushort, bh);
    l = __builtin_bit_cast(ushort, bl);
}
__device__ __forceinline__ ushort bf16bits(float x) {
    return __builtin_bit_cast(ushort, __float2bfloat16(x));
}
__device__ __forceinline__ float bits_to_f(ushort v) {
    return __builtin_bit_cast(float, ((uint)v) << 16);
}
__device__ __forceinline__ short8 lds_frag(const ushort* p) {
    V8 v; v.u = *(const uint4*)p; return v.s;
}

// Frag layout for all prepped weights: elem (k,n) of mat m lives at
//   m*65536 + ((tg*8+ks)*64 + lane)*8 + j
// with tg=n>>4, lr=n&15, ks=k>>5, quad=(k>>3)&3, j=k&7, lane=quad*16+lr.
// Mats: 0=mlp_w1 1=mlp_w2 2=wq 3=wk 4=wv 5=out_w 6=fc_out_w[0:256] 7=[256:512]

// ---------------------------------------------------------------------------
// Dispatch 1: wprep only (64 blocks x 512 thr, two 256-thr jobs per block).
// MUST be its own dispatch: featproj/fused3 read its output.
// ---------------------------------------------------------------------------
__global__ __launch_bounds__(512) void k_wprep(
    const float* __restrict__ mlp_w1, const float* __restrict__ mlp_w2,
    const float* __restrict__ wq, const float* __restrict__ wk,
    const float* __restrict__ wv, const float* __restrict__ out_w,
    const float* __restrict__ fc_out_w,
    ushort* __restrict__ hi, ushort* __restrict__ lo) {
    __shared__ __align__(16) float xs2[2][32 * 132];
    int bx = blockIdx.x, t = threadIdx.x;
    int half = t >> 8, tl = t & 255;
    int job = bx * 2 + half;                      // 0..127
    int m = job >> 4, ks = (job >> 1) & 7, nh = job & 1;
    const float* W = m == 0 ? mlp_w1 : m == 1 ? mlp_w2 : m == 2 ? wq :
                     m == 3 ? wk : m == 4 ? wv : m == 5 ? out_w :
                     m == 6 ? fc_out_w : fc_out_w + 65536;
    ushort* Hm = hi + m * 65536;
    ushort* Lm = lo + m * 65536;
    float* xs = xs2[half];
    #pragma unroll
    for (int p = 0; p < 4; ++p) {
        int idx = p * 256 + tl;
        int row = idx >> 5, c4 = (idx & 31) * 4;
        *(float4*)(xs + row * 132 + c4) =
            *(const float4*)(W + (ks * 32 + row) * 256 + nh * 128 + c4);
    }
    __syncthreads();
    int lane = tl & 63, lr = lane & 15, quad = lane >> 4;
    #pragma unroll
    for (int it = 0; it < 2; ++it) {
        int tgl = (tl >> 6) + 4 * it;
        int tg = nh * 8 + tgl;
        int nl = tgl * 16 + lr;
        ushort hb[8], lb[8];
        #pragma unroll
        for (int j = 0; j < 8; ++j)
            split_bf16(xs[(quad * 8 + j) * 132 + nl], hb[j], lb[j]);
        uint4 ph = { (uint)hb[0] | ((uint)hb[1] << 16), (uint)hb[2] | ((uint)hb[3] << 16),
                     (uint)hb[4] | ((uint)hb[5] << 16), (uint)hb[6] | ((uint)hb[7] << 16) };
        uint4 pl = { (uint)lb[0] | ((uint)lb[1] << 16), (uint)lb[2] | ((uint)lb[3] << 16),
                     (uint)lb[4] | ((uint)lb[5] << 16), (uint)lb[6] | ((uint)lb[7] << 16) };
        int idx = ((tg * 8 + ks) * 64 + lane) * 8;
        *(uint4*)(Hm + idx) = ph;
        *(uint4*)(Lm + idx) = pl;
    }
}

// ---------------------------------------------------------------------------
// Dispatch 2: blocks 0..63 = featproj (stage once, 8 waves cover all jobs);
//             blocks 64..319 = fused3 (mlp1->mlp2->qkv, per-head bf16 out,
//             V pre-transposed). Both only READ wf_hi/wf_lo. 512 threads.
// ---------------------------------------------------------------------------
__global__ __launch_bounds__(512) void k_p2(
    const float* __restrict__ memory_w, const float* __restrict__ X,
    const ushort* __restrict__ Whi, const ushort* __restrict__ Wlo,
    const float* __restrict__ b1, const float* __restrict__ b2,
    const float* __restrict__ Bq, const float* __restrict__ Bk,
    const float* __restrict__ Bv,
    float* __restrict__ A, float* __restrict__ Bm,
    ushort* __restrict__ Qn, ushort* __restrict__ Kn, ushort* __restrict__ Vt) {
    __shared__ __align__(16) union {
        struct { ushort xhi[16 * 264], xlo[16 * 264]; } f;   // featproj 16.9 KB
        struct {
            ushort aHi[16 * 264], aLo[16 * 264];
            ushort bHi[16 * 264], bLo[16 * 264];
        } g;                                                  // fused3 33.8 KB
    } sm;
    int bx = blockIdx.x, t = threadIdx.x;
    if (bx < 64) {
        // ---- featproj: rt = bx; one staged tile serves all 8 (msel,cq)
        int rt = bx;
        #pragma unroll
        for (int ii = 0; ii < 2; ++ii) {
            int f4 = ii * 512 + t;
            int rr = f4 >> 6, c = (f4 & 63) * 4;
            int r = rt * 16 + rr;
            int h = r >> 7, n = r & 127;
            float4 xv = *(const float4*)(memory_w + n * 2048 + h * 256 + c);
            ushort hh[4], ll[4];
            split_bf16(xv.x, hh[0], ll[0]); split_bf16(xv.y, hh[1], ll[1]);
            split_bf16(xv.z, hh[2], ll[2]); split_bf16(xv.w, hh[3], ll[3]);
            uint2 ph = { (uint)hh[0] | ((uint)hh[1] << 16), (uint)hh[2] | ((uint)hh[3] << 16) };
            uint2 pl = { (uint)ll[0] | ((uint)ll[1] << 16), (uint)ll[2] | ((uint)ll[3] << 16) };
            *(uint2*)(sm.f.xhi + rr * 264 + c) = ph;
            *(uint2*)(sm.f.xlo + rr * 264 + c) = pl;
        }
        __syncthreads();
        int lane = t & 63, w = t >> 6;
        int lr = lane & 15, quad = lane >> 4;
        int msel = w & 1, cq = w >> 1;
        const uint4* H4 = (const uint4*)(Whi + (6 + msel) * 65536);
        const uint4* L4 = (const uint4*)(Wlo + (6 + msel) * 65536);
        const ushort* ah = sm.f.xhi + lr * 264 + quad * 8;
        const ushort* al = sm.f.xlo + lr * 264 + quad * 8;
        float* O = msel ? Bm : A;
        #pragma unroll
        for (int i = 0; i < 4; ++i) {
            int tg = cq * 4 + i;
            f32x4 acc = {};
            #pragma unroll
            for (int ks = 0; ks < 8; ++ks) {
                short8 a_h = lds_frag(ah + ks * 32);
                short8 a_l = lds_frag(al + ks * 32);
                int off = (tg * 8 + ks) * 64 + lane;
                V8 bh, bl; bh.u = H4[off]; bl.u = L4[off];
                acc = __builtin_amdgcn_mfma_f32_16x16x32_bf16(a_h, bh.s, acc, 0, 0, 0);
                acc = __builtin_amdgcn_mfma_f32_16x16x32_bf16(a_l, bh.s, acc, 0, 0, 0);
                acc = __builtin_amdgcn_mfma_f32_16x16x32_bf16(a_h, bl.s, acc, 0, 0, 0);
            }
            int n0 = tg * 16 + lr;
            #pragma unroll
            for (int r = 0; r < 4; ++r)
                O[(rt * 16 + quad * 4 + r) * 256 + n0] = acc[r];
        }
        return;
    }
    // ================= fused3 =================
    int r0 = (bx - 64) * 16;
    int lane = t & 63, w = t >> 6, lr = lane & 15, quad = lane >> 4;
    #pragma unroll
    for (int ii = 0; ii < 2; ++ii) {
        int f4 = ii * 512 + t;
        int row = f4 >> 6, c = (f4 & 63) * 4;
        float4 xv = *(const float4*)(X + (r0 + row) * 256 + c);
        ushort h4[4], l4[4];
        split_bf16(xv.x, h4[0], l4[0]); split_bf16(xv.y, h4[1], l4[1]);
        split_bf16(xv.z, h4[2], l4[2]); split_bf16(xv.w, h4[3], l4[3]);
        uint2 ph = { (uint)h4[0] | ((uint)h4[1] << 16), (uint)h4[2] | ((uint)h4[3] << 16) };
        uint2 pl = { (uint)l4[0] | ((uint)l4[1] << 16), (uint)l4[2] | ((uint)l4[3] << 16) };
        *(uint2*)(sm.g.aHi + row * 264 + c) = ph;
        *(uint2*)(sm.g.aLo + row * 264 + c) = pl;
    }
    __syncthreads();
    int aoff = lr * 264 + quad * 8;
    // stage 1: mlp1 + gelu
    {
        const uint4* H4 = (const uint4*)(Whi + 0 * 65536);
        const uint4* L4 = (const uint4*)(Wlo + 0 * 65536);
        f32x4 acc[2] = {};
        #pragma unroll
        for (int ks = 0; ks < 8; ++ks) {
            short8 a_h = lds_frag(sm.g.aHi + aoff + ks * 32);
            short8 a_l = lds_frag(sm.g.aLo + aoff + ks * 32);
            #pragma unroll
            for (int ti = 0; ti < 2; ++ti) {
                int off = ((w * 2 + ti) * 8 + ks) * 64 + lane;
                V8 bh, bl; bh.u = H4[off]; bl.u = L4[off];
                acc[ti] = __builtin_amdgcn_mfma_f32_16x16x32_bf16(a_h, bh.s, acc[ti], 0, 0, 0);
                acc[ti] = __builtin_amdgcn_mfma_f32_16x16x32_bf16(a_l, bh.s, acc[ti], 0, 0, 0);
                acc[ti] = __builtin_amdgcn_mfma_f32_16x16x32_bf16(a_h, bl.s, acc[ti], 0, 0, 0);
            }
        }
        #pragma unroll
        for (int ti = 0; ti < 2; ++ti) {
            int n0 = (w * 2 + ti) * 16 + lr;
            float bb = b1[n0];
            #pragma unroll
            for (int r = 0; r < 4; ++r) {
                float o = gelu_f(acc[ti][r] + bb);
                ushort hh, ll; split_bf16(o, hh, ll);
                int ad = (quad * 4 + r) * 264 + n0;
                sm.g.bHi[ad] = hh; sm.g.bLo[ad] = ll;
            }
        }
    }
    __syncthreads();
    // stage 2: mlp2
    {
        const uint4* H4 = (const uint4*)(Whi + 1 * 65536);
        const uint4* L4 = (const uint4*)(Wlo + 1 * 65536);
        f32x4 acc[2] = {};
        #pragma unroll
        for (int ks = 0; ks < 8; ++ks) {
            short8 a_h = lds_frag(sm.g.bHi + aoff + ks * 32);
            short8 a_l = lds_frag(sm.g.bLo + aoff + ks * 32);
            #pragma unroll
            for (int ti = 0; ti < 2; ++ti) {
                int off = ((w * 2 + ti) * 8 + ks) * 64 + lane;
                V8 bh, bl; bh.u = H4[off]; bl.u = L4[off];
                acc[ti] = __builtin_amdgcn_mfma_f32_16x16x32_bf16(a_h, bh.s, acc[ti], 0, 0, 0);
                acc[ti] = __builtin_amdgcn_mfma_f32_16x16x32_bf16(a_l, bh.s, acc[ti], 0, 0, 0);
                acc[ti] = __builtin_amdgcn_mfma_f32_16x16x32_bf16(a_h, bl.s, acc[ti], 0, 0, 0);
            }
        }
        __syncthreads();
        #pragma unroll
        for (int ti = 0; ti < 2; ++ti) {
            int n0 = (w * 2 + ti) * 16 + lr;
            float bb = b2[n0];
            #pragma unroll
            for (int r = 0; r < 4; ++r) {
                float o = acc[ti][r] + bb;
                ushort hh, ll; split_bf16(o, hh, ll);
                int ad = (quad * 4 + r) * 264 + n0;
                sm.g.aHi[ad] = hh; sm.g.aLo[ad] = ll;
            }
        }
    }
    __syncthreads();
    // stage 3: qkv -> bf16 global, per-head layouts (V pre-transposed)
    {
        const uint4* Hq = (const uint4*)(Whi + 2 * 65536);
        const uint4* Lq = (const uint4*)(Wlo + 2 * 65536);
        const uint4* Hk = (const uint4*)(Whi + 3 * 65536);
        const uint4* Lk = (const uint4*)(Wlo + 3 * 65536);
        const uint4* Hv = (const uint4*)(Whi + 4 * 65536);
        const uint4* Lv = (const uint4*)(Wlo + 4 * 65536);
        f32x4 aq[2] = {}, ak[2] = {}, av[2] = {};
        #pragma unroll 2
        for (int ks = 0; ks < 8; ++ks) {
            short8 a_h = lds_frag(sm.g.aHi + aoff + ks * 32);
            short8 a_l = lds_frag(sm.g.aLo + aoff + ks * 32);
            #pragma unroll
            for (int ti = 0; ti < 2; ++ti) {
                int off = ((w * 2 + ti) * 8 + ks) * 64 + lane;
                V8 qh, ql, kh, kl, vh, vl;
                qh.u = Hq[off]; ql.u = Lq[off];
                kh.u = Hk[off]; kl.u = Lk[off];
                vh.u = Hv[off]; vl.u = Lv[off];
                aq[ti] = __builtin_amdgcn_mfma_f32_16x16x32_bf16(a_h, qh.s, aq[ti], 0, 0, 0);
                aq[ti] = __builtin_amdgcn_mfma_f32_16x16x32_bf16(a_l, qh.s, aq[ti], 0, 0, 0);
                aq[ti] = __builtin_amdgcn_mfma_f32_16x16x32_bf16(a_h, ql.s, aq[ti], 0, 0, 0);
                ak[ti] = __builtin_amdgcn_mfma_f32_16x16x32_bf16(a_h, kh.s, ak[ti], 0, 0, 0);
                ak[ti] = __builtin_amdgcn_mfma_f32_16x16x32_bf16(a_l, kh.s, ak[ti], 0, 0, 0);
                ak[ti] = __builtin_amdgcn_mfma_f32_16x16x32_bf16(a_h, kl.s, ak[ti], 0, 0, 0);
                av[ti] = __builtin_amdgcn_mfma_f32_16x16x32_bf16(a_h, vh.s, av[ti], 0, 0, 0);
                av[ti] = __builtin_amdgcn_mfma_f32_16x16x32_bf16(a_l, vh.s, av[ti], 0, 0, 0);
                av[ti] = __builtin_amdgcn_mfma_f32_16x16x32_bf16(a_h, vl.s, av[ti], 0, 0, 0);
            }
        }
        #pragma unroll
        for (int ti = 0; ti < 2; ++ti) {
            int n0 = (w * 2 + ti) * 16 + lr;
            int hh = n0 >> 5, dk = n0 & 31;
            float vbq = Bq[n0], vbk = Bk[n0], vbv = Bv[n0];
            #pragma unroll
            for (int r = 0; r < 4; ++r) {
                int row = r0 + quad * 4 + r;
                int bb = row >> 7, n = row & 127;
                int bh_ = bb * 8 + hh;
                Qn[(bh_ * 128 + n) * 32 + dk] = bf16bits(aq[ti][r] + vbq);
                Kn[(bh_ * 128 + n) * 32 + dk] = bf16bits(ak[ti][r] + vbk);
                Vt[(bh_ * 32 + dk) * 128 + n] = bf16bits(av[ti][r] + vbv);
            }
        }
    }
}

// ---------------------------------------------------------------------------
// Dispatch 3: conn (32i x 16j tiles). 256 blocks x 512 thr.
// ---------------------------------------------------------------------------
__global__ __launch_bounds__(512) void k_conn(
    const float* __restrict__ A, const float* __restrict__ Bmat,
    const float* __restrict__ fc_out_b, const float* __restrict__ fc_cat_w,
    const float* __restrict__ fc_cat_b, const float* __restrict__ gumbel_u,
    ushort* __restrict__ maskb) {
    __shared__ __align__(16) float sA[16 * 260], sB[32 * 260];
    int bx = blockIdx.x, t = threadIdx.x;
    int h = bx >> 5;
    int rem = bx & 31;
    int it = rem >> 3, jt = rem & 7;    // it 0..3, jt 0..7
    int i0 = it * 32, j0 = jt * 16;
    int jl = t & 15, il = t >> 4;       // jl 0..15, il 0..31
    #pragma unroll
    for (int p = 0; p < 6; ++p) {
        int id2 = p * 512 + t;          // 0..3071
        if (id2 < 1024) {
            int rr = id2 >> 6, c = (id2 & 63) * 4;
            *(float4*)(sA + rr * 260 + c) =
                *(const float4*)(A + (h * 128 + j0 + rr) * 256 + c);
        } else {
            int id3 = id2 - 1024;
            int rr = id3 >> 6, c = (id3 & 63) * 4;
            float4 bv = *(const float4*)(Bmat + (h * 128 + i0 + rr) * 256 + c);
            float4 fb = *(const float4*)(fc_out_b + c);
            bv.x += fb.x; bv.y += fb.y; bv.z += fb.z; bv.w += fb.w;
            *(float4*)(sB + rr * 260 + c) = bv;
        }
    }
    __syncthreads();
    const float* Ar = sA + jl * 260;
    const float* Br = sB + il * 260;
    float l0 = fc_cat_b[0], l1 = fc_cat_b[1];
    #pragma unroll 4
    for (int d4 = 0; d4 < 64; ++d4) {
        int d = d4 * 4;
        float4 av = *(const float4*)(Ar + d);
        float4 bv = *(const float4*)(Br + d);
        float4 cwA = *(const float4*)(fc_cat_w + d * 2);
        float4 cwB = *(const float4*)(fc_cat_w + d * 2 + 4);
        float h0 = fmaxf(av.x + bv.x, 0.f);
        float h1 = fmaxf(av.y + bv.y, 0.f);
        float h2 = fmaxf(av.z + bv.z, 0.f);
        float h3 = fmaxf(av.w + bv.w, 0.f);
        l0 += h0 * cwA.x + h1 * cwA.z + h2 * cwB.x + h3 * cwB.z;
        l1 += h0 * cwA.y + h1 * cwA.w + h2 * cwB.y + h3 * cwB.w;
    }
    int i = i0 + il, j = j0 + jl;
    float2 uu = *(const float2*)(gumbel_u + ((h * 128 + i) * 128 + j) * 2);
    float g0 = -logf(-logf(uu.x + 1e-10f) + 1e-10f);
    float g1 = -logf(-logf(uu.y + 1e-10f) + 1e-10f);
    bool on = (l1 + g1) > (l0 + g0);
    maskb[(h * 128 + i) * 128 + j] = bf16bits(on ? 0.f : -1e9f);
}

// ---------------------------------------------------------------------------
// Dispatch 4: MFMA attention on per-head bf16 Q/K/V. grid 512 = (b, h, rh);
// 256 thr = 4 waves; wave w -> row tile rt = rh*4 + w. V pre-transposed in
// global (no LDS V stage, no __syncthreads). f32 AO output (round-0 layout).
// ---------------------------------------------------------------------------
__global__ __launch_bounds__(256) void k_attn_mfma(
    const ushort* __restrict__ Qn, const ushort* __restrict__ Kn,
    const ushort* __restrict__ Vt, const ushort* __restrict__ maskb,
    float* __restrict__ AO) {
    __shared__ __align__(16) ushort ps[64 * 136];
    int bx = blockIdx.x;
    int b = bx >> 4, h = (bx >> 1) & 7, rh = bx & 1;
    int t = threadIdx.x;
    int lane = t & 63, w = t >> 6, lr = lane & 15, quad = lane >> 4;
    int rt = rh * 4 + w;
    int bh_ = b * 8 + h;
    V8 af;
    af.u = *(const uint4*)(Qn + (bh_ * 128 + rt * 16 + lr) * 32 + quad * 8);
    f32x4 s[8];
    #pragma unroll
    for (int ct = 0; ct < 8; ++ct) {
        V8 bf_;
        bf_.u = *(const uint4*)(Kn + (bh_ * 128 + ct * 16 + lr) * 32 + quad * 8);
        f32x4 z = {0.f, 0.f, 0.f, 0.f};
        s[ct] = __builtin_amdgcn_mfma_f32_16x16x32_bf16(af.s, bf_.s, z, 0, 0, 0);
    }
    const float scale = 0.17677669529663687f;  // 32^-0.5
    const ushort* mrow = maskb + h * 16384;
    #pragma unroll
    for (int r = 0; r < 4; ++r) {
        int lrow = w * 16 + quad * 4 + r;
        int grow = rt * 16 + quad * 4 + r;
        float sv[8];
        float mx = -3.0e38f;
        #pragma unroll
        for (int ct = 0; ct < 8; ++ct) {
            float bias = bits_to_f(mrow[grow * 128 + ct * 16 + lr]);
            sv[ct] = s[ct][r] * scale + bias;
            mx = fmaxf(mx, sv[ct]);
        }
        mx = fmaxf(mx, __shfl_xor(mx, 1));
        mx = fmaxf(mx, __shfl_xor(mx, 2));
        mx = fmaxf(mx, __shfl_xor(mx, 4));
        mx = fmaxf(mx, __shfl_xor(mx, 8));
        float sum = 0.f;
        #pragma unroll
        for (int ct = 0; ct < 8; ++ct) {
            sv[ct] = __expf(sv[ct] - mx);
            sum += sv[ct];
        }
        sum += __shfl_xor(sum, 1);
        sum += __shfl_xor(sum, 2);
        sum += __shfl_xor(sum, 4);
        sum += __shfl_xor(sum, 8);
        float iv = 1.f / sum;
        #pragma unroll
        for (int ct = 0; ct < 8; ++ct)
            ps[lrow * 136 + ct * 16 + lr] = bf16bits(sv[ct] * iv);
    }
    f32x4 o0 = {}, o1 = {};
    #pragma unroll
    for (int kk = 0; kk < 4; ++kk) {
        short8 pa = lds_frag(ps + (w * 16 + lr) * 136 + kk * 32 + quad * 8);
        V8 v0, v1;
        v0.u = *(const uint4*)(Vt + (bh_ * 32 + lr) * 128 + kk * 32 + quad * 8);
        v1.u = *(const uint4*)(Vt + (bh_ * 32 + 16 + lr) * 128 + kk * 32 + quad * 8);
        o0 = __builtin_amdgcn_mfma_f32_16x16x32_bf16(pa, v0.s, o0, 0, 0, 0);
        o1 = __builtin_amdgcn_mfma_f32_16x16x32_bf16(pa, v1.s, o1, 0, 0, 0);
    }
    #pragma unroll
    for (int r = 0; r < 4; ++r) {
        int grow = rt * 16 + quad * 4 + r;
        float* op = AO + b * 32768 + grow * 256 + h * 32;
        op[lr] = o0[r];
        op[16 + lr] = o1[r];
    }
}

// ---------------------------------------------------------------------------
// Dispatch 5: out-proj GEMM. grid (256 rowtiles, 4 colquads), 256 thr.
// (round-0 structure: LDS-staged f32 A tile, 4096 waves)
// ---------------------------------------------------------------------------
__global__ __launch_bounds__(256) void k_gemm16(
    const float* __restrict__ X, const ushort* __restrict__ Whi,
    const ushort* __restrict__ Wlo, const float* __restrict__ bias,
    float* __restrict__ Y) {
    __shared__ __align__(16) ushort xhi[16 * 264], xlo[16 * 264];
    int t = threadIdx.x;
    int r0 = blockIdx.x * 16;
    #pragma unroll
    for (int ii = 0; ii < 4; ++ii) {
        int f4 = ii * 256 + t;
        int row = f4 >> 6, c = (f4 & 63) * 4;
        float4 xv = *(const float4*)(X + (r0 + row) * 256 + c);
        ushort h[4], l[4];
        split_bf16(xv.x, h[0], l[0]); split_bf16(xv.y, h[1], l[1]);
        split_bf16(xv.z, h[2], l[2]); split_bf16(xv.w, h[3], l[3]);
        uint2 ph = { (uint)h[0] | ((uint)h[1] << 16), (uint)h[2] | ((uint)h[3] << 16) };
        uint2 pl = { (uint)l[0] | ((uint)l[1] << 16), (uint)l[2] | ((uint)l[3] << 16) };
        *(uint2*)(xhi + row * 264 + c) = ph;
        *(uint2*)(xlo + row * 264 + c) = pl;
    }
    __syncthreads();
    int l = t & 63, w = t >> 6;
    int lr = l & 15, quad = l >> 4;
    int tg = blockIdx.y * 4 + w;
    const ushort* ah = xhi + lr * 264 + quad * 8;
    const ushort* al = xlo + lr * 264 + quad * 8;
    const uint4* H4 = (const uint4*)Whi;
    const uint4* L4 = (const uint4*)Wlo;
    f32x4 acc = {};
    #pragma unroll
    for (int ks = 0; ks < 8; ++ks) {
        short8 a_h = lds_frag(ah + ks * 32);
        short8 a_l = lds_frag(al + ks * 32);
        int off = (tg * 8 + ks) * 64 + l;
        V8 bh, bl; bh.u = H4[off]; bl.u = L4[off];
        acc = __builtin_amdgcn_mfma_f32_16x16x32_bf16(a_h, bh.s, acc, 0, 0, 0);
        acc = __builtin_amdgcn_mfma_f32_16x16x32_bf16(a_l, bh.s, acc, 0, 0, 0);
        acc = __builtin_amdgcn_mfma_f32_16x16x32_bf16(a_h, bl.s, acc, 0, 0, 0);
    }
    int n0 = tg * 16 + lr;
    float bs = bias[n0];
    #pragma unroll
    for (int r = 0; r < 4; ++r)
        Y[(r0 + quad * 4 + r) * 256 + n0] = acc[r] + bs;
}

// ---------------------------------------------------------------------------
extern "C" void kernel_launch(void* const* d_in, const int* in_sizes, int n_in,
                              void* d_out, int out_size, void* d_ws, size_t ws_size,
                              hipStream_t stream) {
    const float* x        = (const float*)d_in[0];
    const float* gumbel_u = (const float*)d_in[1];
    const float* memory_w = (const float*)d_in[2];
    const float* fc_out_w = (const float*)d_in[3];
    const float* fc_out_b = (const float*)d_in[4];
    const float* fc_cat_w = (const float*)d_in[5];
    const float* fc_cat_b = (const float*)d_in[6];
    const float* wq       = (const float*)d_in[7];
    const float* bq       = (const float*)d_in[8];
    const float* wk       = (const float*)d_in[9];
    const float* bk       = (const float*)d_in[10];
    const float* wv_      = (const float*)d_in[11];
    const float* bv_      = (const float*)d_in[12];
    const float* out_w    = (const float*)d_in[13];
    const float* out_b    = (const float*)d_in[14];
    const float* mlp_w1   = (const float*)d_in[15];
    const float* mlp_b1   = (const float*)d_in[16];
    const float* mlp_w2   = (const float*)d_in[17];
    const float* mlp_b2   = (const float*)d_in[18];

    // Workspace (float offsets).
    float* ws     = (float*)d_ws;
    float* A      = ws;                        //        0 .. 262144
    float* Bm     = ws + 262144;               //   262144 .. 524288
    ushort* mask  = (ushort*)(ws + 524288);    //   524288 .. 557056 (65536 u16)
    ushort* qn    = (ushort*)(ws + 589824);    //   589824 .. 1114112
    ushort* kn    = (ushort*)(ws + 1114112);   //  1114112 .. 1638400
    ushort* vt    = (ushort*)(ws + 1638400);   //  1638400 .. 2162688
    float* ao     = ws + 2162688;              //  2162688 .. 3211264
    ushort* wf_hi = (ushort*)(ws + 3211264);   //  3211264 .. 3473408
    ushort* wf_lo = wf_hi + 8 * 65536;         //  3473408 .. 3735552
    float* out    = (float*)d_out;

    // DAG: wprep -> p2(featproj||fused3) -> conn -> attn -> gemm16.
    k_wprep<<<dim3(64), dim3(512), 0, stream>>>(
        mlp_w1, mlp_w2, wq, wk, wv_, out_w, fc_out_w, wf_hi, wf_lo);
    k_p2<<<dim3(320), dim3(512), 0, stream>>>(
        memory_w, x, wf_hi, wf_lo, mlp_b1, mlp_b2, bq, bk, bv_,
        A, Bm, qn, kn, vt);
    k_conn<<<dim3(256), dim3(512), 0, stream>>>(
        A, Bm, fc_out_b, fc_cat_w, fc_cat_b, gumbel_u, mask);
    k_attn_mfma<<<dim3(512), dim3(256), 0, stream>>>(qn, kn, vt, mask, ao);
    k_gemm16<<<dim3(256, 4), dim3(256), 0, stream>>>(ao, wf_hi + 5 * 65536,
                                                     wf_lo + 5 * 65536, out_b, out);
}